// Round 9
// baseline (269.551 us; speedup 1.0000x reference)
//
#include <hip/hip_runtime.h>
#include <hip/hip_bf16.h>
#include <cstdint>
#include <cstddef>

typedef unsigned short ushort_t;
typedef __bf16 bf16x8 __attribute__((ext_vector_type(8)));
typedef float f32x4 __attribute__((ext_vector_type(4)));

#define D_MODEL 1024
#define D_FF 4096
#define BB 2
#define SS 2048
#define NH 16
#define MROWS (BB * SS) /* 4096 */
#define KVBLK 64

__device__ __forceinline__ ushort_t f2bf(float f) {
  union { float f; unsigned u; } x; x.f = f;
  unsigned r = x.u + 0x7fffu + ((x.u >> 16) & 1u);
  return (ushort_t)(r >> 16);
}

__device__ __forceinline__ void gload_lds16(const void* g, void* l) {
  __builtin_amdgcn_global_load_lds((const __attribute__((address_space(1))) void*)g,
                                   (__attribute__((address_space(3))) void*)l, 16, 0, 0);
}

__device__ __forceinline__ float dpp_sum16(float x) {
  int v;
  v = __builtin_amdgcn_update_dpp(0, __float_as_int(x), 0xB1, 0xF, 0xF, true);
  x += __int_as_float(v);
  v = __builtin_amdgcn_update_dpp(0, __float_as_int(x), 0x4E, 0xF, 0xF, true);
  x += __int_as_float(v);
  v = __builtin_amdgcn_update_dpp(0, __float_as_int(x), 0x141, 0xF, 0xF, true);
  x += __int_as_float(v);
  v = __builtin_amdgcn_update_dpp(0, __float_as_int(x), 0x140, 0xF, 0xF, true);
  x += __int_as_float(v);
  return x;
}

// ---------------- LayerNorm (fp32 in -> bf16 out) ----------------
__global__ __launch_bounds__(256) void ln_bf16_kernel(
    const float* __restrict__ x, const float* __restrict__ w,
    const float* __restrict__ b, ushort_t* __restrict__ out) {
  int row = blockIdx.x;
  int tid = threadIdx.x;
  int lane = tid & 63, wid = tid >> 6;
  const float4 v = ((const float4*)(x + (size_t)row * D_MODEL))[tid];
  float s = v.x + v.y + v.z + v.w;
  __shared__ float red[8];
  #pragma unroll
  for (int o = 32; o > 0; o >>= 1) s += __shfl_down(s, o);
  if (lane == 0) red[wid] = s;
  __syncthreads();
  float mu = (red[0] + red[1] + red[2] + red[3]) * (1.0f / D_MODEL);
  float d0 = v.x - mu, d1 = v.y - mu, d2 = v.z - mu, d3 = v.w - mu;
  float sq = d0 * d0 + d1 * d1 + d2 * d2 + d3 * d3;
  #pragma unroll
  for (int o = 32; o > 0; o >>= 1) sq += __shfl_down(sq, o);
  if (lane == 0) red[4 + wid] = sq;
  __syncthreads();
  float var = (red[4] + red[5] + red[6] + red[7]) * (1.0f / D_MODEL);
  float rstd = rsqrtf(var + 1e-5f);
  const float4 wv = ((const float4*)w)[tid];
  const float4 bv = ((const float4*)b)[tid];
  ushort4 o4;
  o4.x = f2bf(d0 * rstd * wv.x + bv.x);
  o4.y = f2bf(d1 * rstd * wv.y + bv.y);
  o4.z = f2bf(d2 * rstd * wv.z + bv.z);
  o4.w = f2bf(d3 * rstd * wv.w + bv.w);
  ((ushort4*)(out + (size_t)row * D_MODEL))[tid] = o4;
}

// ---------------- transpose + cast: W[K][N] fp32 -> Wt[N][K] bf16 ----------------
__global__ __launch_bounds__(256) void transpose_cast_kernel(
    const float* __restrict__ W, ushort_t* __restrict__ Wt, int K, int N) {
  __shared__ float tile[32][33];
  int bx = blockIdx.x * 32;  // n
  int by = blockIdx.y * 32;  // k
  int tx = threadIdx.x, ty = threadIdx.y;  // 32 x 8
  #pragma unroll
  for (int i = 0; i < 32; i += 8)
    tile[ty + i][tx] = W[(size_t)(by + ty + i) * N + bx + tx];
  __syncthreads();
  #pragma unroll
  for (int i = 0; i < 32; i += 8)
    Wt[(size_t)(bx + ty + i) * K + by + tx] = f2bf(tile[tx][ty + i]);
}

// ---------------- V transpose: qkv V-slice -> Vt[bh][64 d][SS keys] bf16 ----------------
__global__ __launch_bounds__(256) void vtrans_kernel(
    const ushort_t* __restrict__ qkv, ushort_t* __restrict__ Vt) {
  __shared__ __align__(16) ushort_t T[64 * 64];  // [key][d], chunk-XOR swizzled
  const int tid = threadIdx.x;
  const int bh = blockIdx.y, b = bh >> 4, h = bh & 15;
  const int kv0 = blockIdx.x * 64;
  const ushort_t* Vp = qkv + (size_t)b * SS * 3072 + 2048 + h * 64;
  #pragma unroll
  for (int i = 0; i < 2; i++) {
    int idx = tid * 2 + i;          // chunk index
    int key = idx >> 3, c = idx & 7;
    bf16x8 v = *(const bf16x8*)(Vp + (size_t)(kv0 + key) * 3072 + c * 8);
    *(bf16x8*)(T + key * 64 + ((c ^ (key & 7)) * 8)) = v;
  }
  __syncthreads();
  int d = tid >> 2, kb = tid & 3;
  ushort_t o[16];
  #pragma unroll
  for (int j = 0; j < 16; j++) {
    int key = kb * 16 + j;
    o[j] = T[key * 64 + (((d >> 3) ^ (key & 7)) * 8) + (d & 7)];
  }
  ushort_t* dst = Vt + (size_t)(bh * 64 + d) * SS + kv0 + kb * 16;
  *(bf16x8*)dst = *(bf16x8*)&o[0];
  *(bf16x8*)(dst + 8) = *(bf16x8*)&o[8];
}

// ---------------- GEMM 128x128, BK=32, 4-deep LDS pipeline, counted vmcnt ----------------
// EPI: 0 = bf16 + bias (cols<1024 scaled by Cs for QKV); 1 = bf16 + bias + relu.
template <int EPI>
__global__ __launch_bounds__(256, 2) void gemm128_kernel(
    const ushort_t* __restrict__ A, const ushort_t* __restrict__ Bt,
    const float* __restrict__ bias, const float* __restrict__ resid,
    void* __restrict__ Cout, int M, int N, int K, int NTn) {
  __shared__ __align__(16) ushort_t lds[4][2][4096];  // [buf][A|B][8KB]
  const int tid = threadIdx.x, lane = tid & 63, wid = tid >> 6;
  const int wm = wid >> 1, wn = wid & 1;
  const int rl = lane & 15, cg = lane >> 4;
  int nwg = gridDim.x;
  int q = nwg >> 3, rr = nwg & 7;
  int xcd = blockIdx.x & 7, idx = blockIdx.x >> 3;
  int wgid = (xcd < rr ? xcd * (q + 1) : rr * (q + 1) + (xcd - rr) * q) + idx;
  const int row0 = (wgid / NTn) * 128, col0 = (wgid - (wgid / NTn) * NTn) * 128;
  const int NT = K / 32;

  int soff[2], ldso[2];
  #pragma unroll
  for (int i = 0; i < 2; i++) {
    int ci = wid * 128 + i * 64 + lane;
    int P = ci * 16;
    int L = P ^ (((P >> 7) & 7) << 4);
    int row = L >> 6, kc = (L >> 4) & 3;
    soff[i] = row * K + kc * 8;
    ldso[i] = (wid * 128 + i * 64) * 8;
  }

  f32x4 acc[4][4] = {};

  auto stage = [&](int t) {
    int b = t & 3;
    int kk = t * 32;
    #pragma unroll
    for (int i = 0; i < 2; i++) {
      gload_lds16(A + (size_t)row0 * K + kk + soff[i], &lds[b][0][ldso[i]]);
      gload_lds16(Bt + (size_t)col0 * K + kk + soff[i], &lds[b][1][ldso[i]]);
    }
  };

  auto compute = [&](int t) {
    int b = t & 3;
    bf16x8 af[4], bfv[4];
    #pragma unroll
    for (int mi = 0; mi < 4; mi++) {
      int r = wm * 64 + mi * 16 + rl;
      int L = r * 64 + cg * 16;
      int P = L ^ (((L >> 7) & 7) << 4);
      af[mi] = *(const bf16x8*)&lds[b][0][P >> 1];
    }
    #pragma unroll
    for (int ni = 0; ni < 4; ni++) {
      int r = wn * 64 + ni * 16 + rl;
      int L = r * 64 + cg * 16;
      int P = L ^ (((L >> 7) & 7) << 4);
      bfv[ni] = *(const bf16x8*)&lds[b][1][P >> 1];
    }
    __builtin_amdgcn_s_setprio(1);
    #pragma unroll
    for (int mi = 0; mi < 4; mi++)
      #pragma unroll
      for (int ni = 0; ni < 4; ni++)
        acc[mi][ni] = __builtin_amdgcn_mfma_f32_16x16x32_bf16(af[mi], bfv[ni], acc[mi][ni], 0, 0, 0);
    __builtin_amdgcn_s_setprio(0);
  };

  stage(0); stage(1); stage(2);
  for (int t = 0; t < NT; ++t) {
    if (t < NT - 2)       asm volatile("s_waitcnt vmcnt(8)" ::: "memory");
    else if (t == NT - 2) asm volatile("s_waitcnt vmcnt(4)" ::: "memory");
    else                  asm volatile("s_waitcnt vmcnt(0)" ::: "memory");
    __builtin_amdgcn_s_barrier();
    __builtin_amdgcn_sched_barrier(0);
    if (t + 3 < NT) stage(t + 3);
    compute(t);
  }

  ushort_t* out = (ushort_t*)Cout;
  #pragma unroll
  for (int ni = 0; ni < 4; ni++) {
    int col = col0 + wn * 64 + ni * 16 + rl;
    float bv = bias[col];
    float sc = (EPI == 0 && col < 1024) ? 0.18033688011f : 1.0f;
    #pragma unroll
    for (int mi = 0; mi < 4; mi++) {
      int rowb = row0 + wm * 64 + mi * 16 + cg * 4;
      #pragma unroll
      for (int j = 0; j < 4; j++) {
        float v = acc[mi][ni][j] + bv;
        if (EPI == 1) v = fmaxf(v, 0.0f);
        if (EPI == 0) v *= sc;
        out[(size_t)(rowb + j) * N + col] = f2bf(v);
      }
    }
  }
}

// ---------------- GEMM 64x128, BK=32, 3-buffer ring, counted vmcnt ----------------
// For N=1024 shapes (O-proj, FFN2): 512-block grids -> 4 blocks/CU (36KB LDS).
// 4 waves, each 32(M)x64(N), acc[2][4]. fp32 out + bias + residual fused.
__global__ __launch_bounds__(256, 4) void gemm64_kernel(
    const ushort_t* __restrict__ A, const ushort_t* __restrict__ Bt,
    const float* __restrict__ bias, const float* __restrict__ resid,
    float* __restrict__ Cout, int M, int N, int K, int NTn) {
  __shared__ __align__(16) ushort_t lA[3][2048];  // 3 x 4KB
  __shared__ __align__(16) ushort_t lB[3][4096];  // 3 x 8KB
  const int tid = threadIdx.x, lane = tid & 63, wid = tid >> 6;
  const int wm = wid >> 1, wn = wid & 1;
  const int rl = lane & 15, cg = lane >> 4;
  int nwg = gridDim.x;
  int q = nwg >> 3, rr = nwg & 7;
  int xcd = blockIdx.x & 7, idx = blockIdx.x >> 3;
  int wgid = (xcd < rr ? xcd * (q + 1) : rr * (q + 1) + (xcd - rr) * q) + idx;
  const int row0 = (wgid / NTn) * 64, col0 = (wgid - (wgid / NTn) * NTn) * 128;
  const int NT = K / 32;

  // staging offsets: A one chunk/lane (256 chunks), B two chunks/lane (512)
  int soffA, ldsoA, soffB[2], ldsoB[2];
  {
    int ci = wid * 64 + lane;
    int P = ci * 16;
    int L = P ^ (((P >> 7) & 7) << 4);
    soffA = (L >> 6) * K + ((L >> 4) & 3) * 8;
    ldsoA = wid * 512;
  }
  #pragma unroll
  for (int i = 0; i < 2; i++) {
    int ci = wid * 128 + i * 64 + lane;
    int P = ci * 16;
    int L = P ^ (((P >> 7) & 7) << 4);
    soffB[i] = (L >> 6) * K + ((L >> 4) & 3) * 8;
    ldsoB[i] = (wid * 128 + i * 64) * 8;
  }

  f32x4 acc[2][4] = {};

  auto stage = [&](int t, int b) {
    int kk = t * 32;
    gload_lds16(A + (size_t)row0 * K + kk + soffA, &lA[b][ldsoA]);
    gload_lds16(Bt + (size_t)col0 * K + kk + soffB[0], &lB[b][ldsoB[0]]);
    gload_lds16(Bt + (size_t)col0 * K + kk + soffB[1], &lB[b][ldsoB[1]]);
  };

  auto compute = [&](int b) {
    bf16x8 af[2], bfv[4];
    #pragma unroll
    for (int mi = 0; mi < 2; mi++) {
      int r = wm * 32 + mi * 16 + rl;
      int L = r * 64 + cg * 16;
      int P = L ^ (((L >> 7) & 7) << 4);
      af[mi] = *(const bf16x8*)&lA[b][P >> 1];
    }
    #pragma unroll
    for (int ni = 0; ni < 4; ni++) {
      int r = wn * 64 + ni * 16 + rl;
      int L = r * 64 + cg * 16;
      int P = L ^ (((L >> 7) & 7) << 4);
      bfv[ni] = *(const bf16x8*)&lB[b][P >> 1];
    }
    __builtin_amdgcn_s_setprio(1);
    #pragma unroll
    for (int mi = 0; mi < 2; mi++)
      #pragma unroll
      for (int ni = 0; ni < 4; ni++)
        acc[mi][ni] = __builtin_amdgcn_mfma_f32_16x16x32_bf16(af[mi], bfv[ni], acc[mi][ni], 0, 0, 0);
    __builtin_amdgcn_s_setprio(0);
  };

  stage(0, 0); stage(1, 1);
  int sb = 2, cb = 0;
  for (int t = 0; t < NT; ++t) {
    if (t < NT - 1) asm volatile("s_waitcnt vmcnt(3)" ::: "memory");
    else            asm volatile("s_waitcnt vmcnt(0)" ::: "memory");
    __builtin_amdgcn_s_barrier();
    __builtin_amdgcn_sched_barrier(0);
    if (t + 2 < NT) { stage(t + 2, sb); sb = (sb == 2) ? 0 : sb + 1; }
    compute(cb);
    cb = (cb == 2) ? 0 : cb + 1;
  }

  #pragma unroll
  for (int ni = 0; ni < 4; ni++) {
    int col = col0 + wn * 64 + ni * 16 + rl;
    float bv = bias[col];
    #pragma unroll
    for (int mi = 0; mi < 2; mi++) {
      int rowb = row0 + wm * 32 + mi * 16 + cg * 4;
      #pragma unroll
      for (int j = 0; j < 4; j++)
        Cout[(size_t)(rowb + j) * N + col] =
            acc[mi][ni][j] + bv + resid[(size_t)(rowb + j) * N + col];
    }
  }
}

// ---------------- flash attention (K+V LDS double-buffered; static-shift softmax) ----------------
__global__ __launch_bounds__(256) void attn_kernel(
    const ushort_t* __restrict__ qkv, const ushort_t* __restrict__ Vt,
    ushort_t* __restrict__ ctx) {
  __shared__ __align__(16) ushort_t Kl[2][64 * 64];
  __shared__ __align__(16) ushort_t Vl[2][64 * 64];
  __shared__ __align__(16) ushort_t Pl[4][16 * 64];
  const int tid = threadIdx.x, lane = tid & 63, wid = tid >> 6;
  int bid = blockIdx.y * 32 + blockIdx.x;
  int w = (bid & 7) * 128 + (bid >> 3);
  const int bh = w >> 5, qt = w & 31;
  const int b = bh >> 4, h = bh & 15;
  const int q0 = qt * 64 + wid * 16;
  const ushort_t* Qp = qkv + (size_t)b * SS * 3072 + h * 64;
  const ushort_t* Kp = Qp + 1024;
  const ushort_t* Vg = Vt + (size_t)bh * 64 * SS;

  bf16x8 qf[2];
  {
    int qr = q0 + (lane & 15);
    #pragma unroll
    for (int s2 = 0; s2 < 2; s2++)
      qf[s2] = *(const bf16x8*)(Qp + (size_t)qr * 3072 + s2 * 32 + (lane >> 4) * 8);
  }
  float l[4];
  f32x4 acc[4] = {};
  #pragma unroll
  for (int r = 0; r < 4; r++) l[r] = 0.f;

  const int NT = SS / KVBLK;

  int ksrc[2], vsrc[2];
  #pragma unroll
  for (int i = 0; i < 2; i++) {
    int idx = wid * 128 + i * 64 + lane;
    int R = idx >> 3, c = idx & 7;
    int key = (R & 15) * 4 + (R >> 4);
    ksrc[i] = key * 3072 + ((c ^ (R & 7)) * 8);
    vsrc[i] = R * SS + ((c ^ (R & 7)) * 8);
  }
  const int ldsb = wid * 1024;

  auto stageKV = [&](int buf, int t) {
    size_t kvK = (size_t)t * KVBLK * 3072;
    int kvV = t * KVBLK;
    gload_lds16(Kp + kvK + ksrc[0], &Kl[buf][ldsb]);
    gload_lds16(Kp + kvK + ksrc[1], &Kl[buf][ldsb + 512]);
    gload_lds16(Vg + kvV + vsrc[0], &Vl[buf][ldsb]);
    gload_lds16(Vg + kvV + vsrc[1], &Vl[buf][ldsb + 512]);
  };

  auto body = [&](int t, int cb) {
    __syncthreads();
    if (t + 1 < NT) stageKV(cb ^ 1, t + 1);

    f32x4 s4[4] = {};
    #pragma unroll
    for (int g = 0; g < 4; g++) {
      const ushort_t* kr = &Kl[cb][(g * 16 + (lane & 15)) * 64];
      bf16x8 kf0 = *(const bf16x8*)(kr + (((lane >> 4)) ^ ((lane & 15) & 7)) * 8);
      bf16x8 kf1 = *(const bf16x8*)(kr + ((4 + (lane >> 4)) ^ ((lane & 15) & 7)) * 8);
      s4[g] = __builtin_amdgcn_mfma_f32_16x16x32_bf16(qf[0], kf0, s4[g], 0, 0, 0);
      s4[g] = __builtin_amdgcn_mfma_f32_16x16x32_bf16(qf[1], kf1, s4[g], 0, 0, 0);
    }
    const int qrow = (lane >> 4) * 4;
    const int cp = (lane & 15) >> 1, hf = (lane & 15) & 1;
    #pragma unroll
    for (int r = 0; r < 4; r++) {
      float p0 = __builtin_amdgcn_exp2f(s4[0][r]);
      float p1 = __builtin_amdgcn_exp2f(s4[1][r]);
      float p2 = __builtin_amdgcn_exp2f(s4[2][r]);
      float p3 = __builtin_amdgcn_exp2f(s4[3][r]);
      l[r] += (p0 + p1) + (p2 + p3);
      unsigned w0, w1;
      asm("v_cvt_pk_bf16_f32 %0, %1, %2" : "=v"(w0) : "v"(p0), "v"(p1));
      asm("v_cvt_pk_bf16_f32 %0, %1, %2" : "=v"(w1) : "v"(p2), "v"(p3));
      uint2 pw; pw.x = w0; pw.y = w1;
      int qq = qrow + r;
      *(uint2*)(&Pl[wid][qq * 64 + ((cp ^ (qq & 7)) * 8) + hf * 4]) = pw;
    }
    asm volatile("s_waitcnt lgkmcnt(0)" ::: "memory");
    __builtin_amdgcn_sched_barrier(0);
    bf16x8 pf[2];
    {
      int qq = lane & 15;
      #pragma unroll
      for (int ks = 0; ks < 2; ks++) {
        int c = ks * 4 + (lane >> 4);
        pf[ks] = *(const bf16x8*)(&Pl[wid][qq * 64 + ((c ^ (qq & 7)) * 8)]);
      }
    }
    #pragma unroll
    for (int f = 0; f < 4; f++) {
      int d = f * 16 + (lane & 15);
      #pragma unroll
      for (int ks = 0; ks < 2; ks++) {
        int chunk = (ks * 4 + (lane >> 4)) ^ (d & 7);
        bf16x8 vf = *(const bf16x8*)(&Vl[cb][d * 64 + chunk * 8]);
        acc[f] = __builtin_amdgcn_mfma_f32_16x16x32_bf16(pf[ks], vf, acc[f], 0, 0, 0);
      }
    }
  };

  stageKV(0, 0);
  for (int t = 0; t < NT; t += 2) {
    body(t, 0);
    body(t + 1, 1);
  }

  #pragma unroll
  for (int r = 0; r < 4; r++) l[r] = dpp_sum16(l[r]);
  float rl4[4];
  #pragma unroll
  for (int r = 0; r < 4; r++) rl4[r] = 1.0f / l[r];
  #pragma unroll
  for (int f = 0; f < 4; f++)
    #pragma unroll
    for (int r = 0; r < 4; r++) {
      int row = b * SS + q0 + (lane >> 4) * 4 + r;
      int col = h * 64 + f * 16 + (lane & 15);
      ctx[(size_t)row * D_MODEL + col] = f2bf(acc[f][r] * rl4[r]);
    }
}

extern "C" void kernel_launch(void* const* d_in, const int* in_sizes, int n_in,
                              void* d_out, int out_size, void* d_ws, size_t ws_size,
                              hipStream_t stream) {
  const float* x    = (const float*)d_in[0];
  const float* ln1w = (const float*)d_in[1];
  const float* ln1b = (const float*)d_in[2];
  const float* Wq   = (const float*)d_in[3];
  const float* bq   = (const float*)d_in[4];
  const float* Wk   = (const float*)d_in[5];
  const float* bk   = (const float*)d_in[6];
  const float* Wv   = (const float*)d_in[7];
  const float* bv   = (const float*)d_in[8];
  const float* Wo   = (const float*)d_in[9];
  const float* bo   = (const float*)d_in[10];
  const float* ln2w = (const float*)d_in[11];
  const float* ln2b = (const float*)d_in[12];
  const float* W1   = (const float*)d_in[13];
  const float* b1   = (const float*)d_in[14];
  const float* W2   = (const float*)d_in[15];
  const float* b2   = (const float*)d_in[16];

  char* ws = (char*)d_ws;
  size_t off = 0;
  auto alloc = [&](size_t bytes) {
    void* p = ws + off;
    off += (bytes + 255) & ~(size_t)255;
    return p;
  };
  ushort_t* Wt_qkv = (ushort_t*)alloc((size_t)3072 * 1024 * 2);
  ushort_t* Wt_o   = (ushort_t*)alloc((size_t)1024 * 1024 * 2);
  ushort_t* Wt_1   = (ushort_t*)alloc((size_t)4096 * 1024 * 2);
  ushort_t* Wt_2   = (ushort_t*)alloc((size_t)1024 * 4096 * 2);
  float*    bqkv   = (float*)alloc((size_t)3072 * 4);
  ushort_t* qkvb   = (ushort_t*)alloc((size_t)MROWS * 3072 * 2);  // 24 MB
  ushort_t* ctxb   = (ushort_t*)alloc((size_t)MROWS * 1024 * 2);  // 8 MB
  ushort_t* hbuf   = (ushort_t*)alloc((size_t)MROWS * 1024 * 2);
  float*    x2     = (float*)alloc((size_t)MROWS * 1024 * 4);
  ushort_t* Vtb    = (ushort_t*)alloc((size_t)BB * NH * 64 * SS * 2);  // 8 MB
  ushort_t* ff1    = qkvb;  // reuse qkv(24MB)+ctx(8MB) = 32MB for [4096][4096] bf16
  float*    outp   = (float*)d_out;

  dim3 tb(32, 8);
  transpose_cast_kernel<<<dim3(32, 32), tb, 0, stream>>>(Wq, Wt_qkv, 1024, 1024);
  transpose_cast_kernel<<<dim3(32, 32), tb, 0, stream>>>(Wk, Wt_qkv + 1024 * 1024, 1024, 1024);
  transpose_cast_kernel<<<dim3(32, 32), tb, 0, stream>>>(Wv, Wt_qkv + 2 * 1024 * 1024, 1024, 1024);
  transpose_cast_kernel<<<dim3(32, 32), tb, 0, stream>>>(Wo, Wt_o, 1024, 1024);
  transpose_cast_kernel<<<dim3(128, 32), tb, 0, stream>>>(W1, Wt_1, 1024, 4096);
  transpose_cast_kernel<<<dim3(32, 128), tb, 0, stream>>>(W2, Wt_2, 4096, 1024);
  hipMemcpyAsync(bqkv,        bq, 1024 * 4, hipMemcpyDeviceToDevice, stream);
  hipMemcpyAsync(bqkv + 1024, bk, 1024 * 4, hipMemcpyDeviceToDevice, stream);
  hipMemcpyAsync(bqkv + 2048, bv, 1024 * 4, hipMemcpyDeviceToDevice, stream);

  // LN1 -> h
  ln_bf16_kernel<<<MROWS, 256, 0, stream>>>(x, ln1w, ln1b, hbuf);
  // fused QKV GEMM: [4096,1024]x[1024,3072] -> bf16 (Q cols pre-scaled by Cs)
  gemm128_kernel<0><<<dim3(24 * 32), 256, 0, stream>>>(
      hbuf, Wt_qkv, bqkv, nullptr, qkvb, MROWS, 3072, 1024, 24);
  // V transpose -> Vt[bh][64][2048]
  vtrans_kernel<<<dim3(SS / 64, BB * NH), 256, 0, stream>>>(qkvb, Vtb);
  // attention
  attn_kernel<<<dim3(SS / 64, BB * NH), 256, 0, stream>>>(qkvb, Vtb, ctxb);
  // O-proj + bias + residual(x) -> x2 (fp32): 64x128 tiles, 512 blocks
  gemm64_kernel<<<dim3(64 * 8), 256, 0, stream>>>(
      ctxb, Wt_o, bo, x, x2, MROWS, 1024, 1024, 8);
  // LN2 -> h
  ln_bf16_kernel<<<MROWS, 256, 0, stream>>>(x2, ln2w, ln2b, hbuf);
  // FFN1 + relu -> ff1 (bf16)
  gemm128_kernel<1><<<dim3(32 * 32), 256, 0, stream>>>(
      hbuf, Wt_1, b1, nullptr, ff1, MROWS, D_FF, 1024, 32);
  // FFN2 + bias + residual(x2) -> out (fp32): 64x128 tiles, 512 blocks
  gemm64_kernel<<<dim3(64 * 8), 256, 0, stream>>>(
      ff1, Wt_2, b2, x2, outp, MROWS, 1024, 4096, 8);
}

// Round 10
// 253.548 us; speedup vs baseline: 1.0631x; 1.0631x over previous
//
#include <hip/hip_runtime.h>
#include <hip/hip_bf16.h>
#include <cstdint>
#include <cstddef>

typedef unsigned short ushort_t;
typedef __bf16 bf16x8 __attribute__((ext_vector_type(8)));
typedef float f32x4 __attribute__((ext_vector_type(4)));

#define D_MODEL 1024
#define D_FF 4096
#define BB 2
#define SS 2048
#define NH 16
#define MROWS (BB * SS) /* 4096 */
#define KVBLK 64

__device__ __forceinline__ ushort_t f2bf(float f) {
  union { float f; unsigned u; } x; x.f = f;
  unsigned r = x.u + 0x7fffu + ((x.u >> 16) & 1u);
  return (ushort_t)(r >> 16);
}

__device__ __forceinline__ void gload_lds16(const void* g, void* l) {
  __builtin_amdgcn_global_load_lds((const __attribute__((address_space(1))) void*)g,
                                   (__attribute__((address_space(3))) void*)l, 16, 0, 0);
}

__device__ __forceinline__ float dpp_sum16(float x) {
  int v;
  v = __builtin_amdgcn_update_dpp(0, __float_as_int(x), 0xB1, 0xF, 0xF, true);
  x += __int_as_float(v);
  v = __builtin_amdgcn_update_dpp(0, __float_as_int(x), 0x4E, 0xF, 0xF, true);
  x += __int_as_float(v);
  v = __builtin_amdgcn_update_dpp(0, __float_as_int(x), 0x141, 0xF, 0xF, true);
  x += __int_as_float(v);
  v = __builtin_amdgcn_update_dpp(0, __float_as_int(x), 0x140, 0xF, 0xF, true);
  x += __int_as_float(v);
  return x;
}

// ---------------- LayerNorm (fp32 in -> bf16 out) ----------------
__global__ __launch_bounds__(256) void ln_bf16_kernel(
    const float* __restrict__ x, const float* __restrict__ w,
    const float* __restrict__ b, ushort_t* __restrict__ out) {
  int row = blockIdx.x;
  int tid = threadIdx.x;
  int lane = tid & 63, wid = tid >> 6;
  const float4 v = ((const float4*)(x + (size_t)row * D_MODEL))[tid];
  float s = v.x + v.y + v.z + v.w;
  __shared__ float red[8];
  #pragma unroll
  for (int o = 32; o > 0; o >>= 1) s += __shfl_down(s, o);
  if (lane == 0) red[wid] = s;
  __syncthreads();
  float mu = (red[0] + red[1] + red[2] + red[3]) * (1.0f / D_MODEL);
  float d0 = v.x - mu, d1 = v.y - mu, d2 = v.z - mu, d3 = v.w - mu;
  float sq = d0 * d0 + d1 * d1 + d2 * d2 + d3 * d3;
  #pragma unroll
  for (int o = 32; o > 0; o >>= 1) sq += __shfl_down(sq, o);
  if (lane == 0) red[4 + wid] = sq;
  __syncthreads();
  float var = (red[4] + red[5] + red[6] + red[7]) * (1.0f / D_MODEL);
  float rstd = rsqrtf(var + 1e-5f);
  const float4 wv = ((const float4*)w)[tid];
  const float4 bv = ((const float4*)b)[tid];
  ushort4 o4;
  o4.x = f2bf(d0 * rstd * wv.x + bv.x);
  o4.y = f2bf(d1 * rstd * wv.y + bv.y);
  o4.z = f2bf(d2 * rstd * wv.z + bv.z);
  o4.w = f2bf(d3 * rstd * wv.w + bv.w);
  ((ushort4*)(out + (size_t)row * D_MODEL))[tid] = o4;
}

// ---------------- transpose + cast: W[K][N] fp32 -> Wt[N][K] bf16 ----------------
__global__ __launch_bounds__(256) void transpose_cast_kernel(
    const float* __restrict__ W, ushort_t* __restrict__ Wt, int K, int N) {
  __shared__ float tile[32][33];
  int bx = blockIdx.x * 32;  // n
  int by = blockIdx.y * 32;  // k
  int tx = threadIdx.x, ty = threadIdx.y;  // 32 x 8
  #pragma unroll
  for (int i = 0; i < 32; i += 8)
    tile[ty + i][tx] = W[(size_t)(by + ty + i) * N + bx + tx];
  __syncthreads();
  #pragma unroll
  for (int i = 0; i < 32; i += 8)
    Wt[(size_t)(bx + ty + i) * K + by + tx] = f2bf(tile[tx][ty + i]);
}

// ---------------- V transpose: qkv V-slice -> Vt[bh][64 d][SS keys] bf16 ----------------
__global__ __launch_bounds__(256) void vtrans_kernel(
    const ushort_t* __restrict__ qkv, ushort_t* __restrict__ Vt) {
  __shared__ __align__(16) ushort_t T[64 * 64];  // [key][d], chunk-XOR swizzled
  const int tid = threadIdx.x;
  const int bh = blockIdx.y, b = bh >> 4, h = bh & 15;
  const int kv0 = blockIdx.x * 64;
  const ushort_t* Vp = qkv + (size_t)b * SS * 3072 + 2048 + h * 64;
  #pragma unroll
  for (int i = 0; i < 2; i++) {
    int idx = tid * 2 + i;          // chunk index
    int key = idx >> 3, c = idx & 7;
    bf16x8 v = *(const bf16x8*)(Vp + (size_t)(kv0 + key) * 3072 + c * 8);
    *(bf16x8*)(T + key * 64 + ((c ^ (key & 7)) * 8)) = v;
  }
  __syncthreads();
  int d = tid >> 2, kb = tid & 3;
  ushort_t o[16];
  #pragma unroll
  for (int j = 0; j < 16; j++) {
    int key = kb * 16 + j;
    o[j] = T[key * 64 + (((d >> 3) ^ (key & 7)) * 8) + (d & 7)];
  }
  ushort_t* dst = Vt + (size_t)(bh * 64 + d) * SS + kv0 + kb * 16;
  *(bf16x8*)dst = *(bf16x8*)&o[0];
  *(bf16x8*)(dst + 8) = *(bf16x8*)&o[8];
}

// ---------------- GEMM 128x128, BK=32, 4-deep LDS pipeline, counted vmcnt ----------------
// EPI: 0 = bf16 + bias (cols<1024 scaled by Cs for QKV); 1 = bf16 + bias + relu;
//      2 = fp32 + bias + resid (fused); 3 = fp32 partial at Cout + s*M*N (split-K).
template <int EPI>
__global__ __launch_bounds__(256, 2) void gemm128_kernel(
    const ushort_t* __restrict__ A, const ushort_t* __restrict__ Bt,
    const float* __restrict__ bias, const float* __restrict__ resid,
    void* __restrict__ Cout, int M, int N, int K, int NTn, int Ksplit, int MTN) {
  __shared__ __align__(16) ushort_t lds[4][2][4096];  // [buf][A|B][8KB]
  const int tid = threadIdx.x, lane = tid & 63, wid = tid >> 6;
  const int wm = wid >> 1, wn = wid & 1;
  const int rl = lane & 15, cg = lane >> 4;
  int nwg = gridDim.x;
  int q = nwg >> 3, rr = nwg & 7;
  int xcd = blockIdx.x & 7, idx = blockIdx.x >> 3;
  int wgid = (xcd < rr ? xcd * (q + 1) : rr * (q + 1) + (xcd - rr) * q) + idx;
  const int s = wgid / MTN;
  int rem = wgid - s * MTN;
  const int row0 = (rem / NTn) * 128, col0 = (rem - (rem / NTn) * NTn) * 128;
  const int k0 = s * Ksplit;
  const int NT = Ksplit / 32;

  int soff[2], ldso[2];
  #pragma unroll
  for (int i = 0; i < 2; i++) {
    int ci = wid * 128 + i * 64 + lane;
    int P = ci * 16;
    int L = P ^ (((P >> 7) & 7) << 4);
    int row = L >> 6, kc = (L >> 4) & 3;
    soff[i] = row * K + kc * 8;
    ldso[i] = (wid * 128 + i * 64) * 8;
  }

  f32x4 acc[4][4] = {};

  auto stage = [&](int t) {
    int b = t & 3;
    int kk = k0 + t * 32;
    #pragma unroll
    for (int i = 0; i < 2; i++) {
      gload_lds16(A + (size_t)row0 * K + kk + soff[i], &lds[b][0][ldso[i]]);
      gload_lds16(Bt + (size_t)col0 * K + kk + soff[i], &lds[b][1][ldso[i]]);
    }
  };

  auto compute = [&](int t) {
    int b = t & 3;
    bf16x8 af[4], bfv[4];
    #pragma unroll
    for (int mi = 0; mi < 4; mi++) {
      int r = wm * 64 + mi * 16 + rl;
      int L = r * 64 + cg * 16;
      int P = L ^ (((L >> 7) & 7) << 4);
      af[mi] = *(const bf16x8*)&lds[b][0][P >> 1];
    }
    #pragma unroll
    for (int ni = 0; ni < 4; ni++) {
      int r = wn * 64 + ni * 16 + rl;
      int L = r * 64 + cg * 16;
      int P = L ^ (((L >> 7) & 7) << 4);
      bfv[ni] = *(const bf16x8*)&lds[b][1][P >> 1];
    }
    __builtin_amdgcn_s_setprio(1);
    #pragma unroll
    for (int mi = 0; mi < 4; mi++)
      #pragma unroll
      for (int ni = 0; ni < 4; ni++)
        acc[mi][ni] = __builtin_amdgcn_mfma_f32_16x16x32_bf16(af[mi], bfv[ni], acc[mi][ni], 0, 0, 0);
    __builtin_amdgcn_s_setprio(0);
  };

  stage(0); stage(1); stage(2);
  for (int t = 0; t < NT; ++t) {
    if (t < NT - 2)       asm volatile("s_waitcnt vmcnt(8)" ::: "memory");
    else if (t == NT - 2) asm volatile("s_waitcnt vmcnt(4)" ::: "memory");
    else                  asm volatile("s_waitcnt vmcnt(0)" ::: "memory");
    __builtin_amdgcn_s_barrier();
    __builtin_amdgcn_sched_barrier(0);
    if (t + 3 < NT) stage(t + 3);
    compute(t);
  }

  if (EPI == 2) {
    float* out = (float*)Cout;
    #pragma unroll
    for (int ni = 0; ni < 4; ni++) {
      int col = col0 + wn * 64 + ni * 16 + rl;
      float bv = bias[col];
      #pragma unroll
      for (int mi = 0; mi < 4; mi++) {
        int rowb = row0 + wm * 64 + mi * 16 + cg * 4;
        #pragma unroll
        for (int j = 0; j < 4; j++)
          out[(size_t)(rowb + j) * N + col] =
              acc[mi][ni][j] + bv + resid[(size_t)(rowb + j) * N + col];
      }
    }
  } else if (EPI == 3) {
    float* out = (float*)Cout + (size_t)s * M * N;
    #pragma unroll
    for (int ni = 0; ni < 4; ni++) {
      int col = col0 + wn * 64 + ni * 16 + rl;
      #pragma unroll
      for (int mi = 0; mi < 4; mi++) {
        int rowb = row0 + wm * 64 + mi * 16 + cg * 4;
        #pragma unroll
        for (int j = 0; j < 4; j++)
          out[(size_t)(rowb + j) * N + col] = acc[mi][ni][j];
      }
    }
  } else {
    ushort_t* out = (ushort_t*)Cout;
    #pragma unroll
    for (int ni = 0; ni < 4; ni++) {
      int col = col0 + wn * 64 + ni * 16 + rl;
      float bv = bias[col];
      float sc = (EPI == 0 && col < 1024) ? 0.18033688011f : 1.0f;
      #pragma unroll
      for (int mi = 0; mi < 4; mi++) {
        int rowb = row0 + wm * 64 + mi * 16 + cg * 4;
        #pragma unroll
        for (int j = 0; j < 4; j++) {
          float v = acc[mi][ni][j] + bv;
          if (EPI == 1) v = fmaxf(v, 0.0f);
          if (EPI == 0) v *= sc;
          out[(size_t)(rowb + j) * N + col] = f2bf(v);
        }
      }
    }
  }
}

// ---------------- split-K reduce: out = sum(partials) + bias + resid (fp32, N=1024) ----------------
__global__ __launch_bounds__(256) void reduce_kernel(
    const float* __restrict__ p, const float* __restrict__ bias,
    const float* __restrict__ resid, float* __restrict__ out,
    int S, size_t total4, size_t stride4) {
  const float4* p4 = (const float4*)p;
  const float4* r4 = (const float4*)resid;
  const float4* b4 = (const float4*)bias;
  float4* o4 = (float4*)out;
  for (size_t i = (size_t)blockIdx.x * 256 + threadIdx.x; i < total4;
       i += (size_t)gridDim.x * 256) {
    float4 a = r4[i];
    float4 bb = b4[i & 255];
    a.x += bb.x; a.y += bb.y; a.z += bb.z; a.w += bb.w;
    for (int s = 0; s < S; ++s) {
      float4 v = p4[(size_t)s * stride4 + i];
      a.x += v.x; a.y += v.y; a.z += v.z; a.w += v.w;
    }
    o4[i] = a;
  }
}

// ---------------- flash attention (K+V LDS double-buffered; static-shift softmax) ----------------
// No max tracking: Q pre-scaled by Cs=0.125*log2e in QKV epilogue; |s| bounded (C-S), exp2 safe.
__global__ __launch_bounds__(256) void attn_kernel(
    const ushort_t* __restrict__ qkv, const ushort_t* __restrict__ Vt,
    ushort_t* __restrict__ ctx) {
  __shared__ __align__(16) ushort_t Kl[2][64 * 64];
  __shared__ __align__(16) ushort_t Vl[2][64 * 64];
  __shared__ __align__(16) ushort_t Pl[4][16 * 64];
  const int tid = threadIdx.x, lane = tid & 63, wid = tid >> 6;
  int bid = blockIdx.y * 32 + blockIdx.x;
  int w = (bid & 7) * 128 + (bid >> 3);
  const int bh = w >> 5, qt = w & 31;
  const int b = bh >> 4, h = bh & 15;
  const int q0 = qt * 64 + wid * 16;
  const ushort_t* Qp = qkv + (size_t)b * SS * 3072 + h * 64;
  const ushort_t* Kp = Qp + 1024;
  const ushort_t* Vg = Vt + (size_t)bh * 64 * SS;

  bf16x8 qf[2];
  {
    int qr = q0 + (lane & 15);
    #pragma unroll
    for (int s2 = 0; s2 < 2; s2++)
      qf[s2] = *(const bf16x8*)(Qp + (size_t)qr * 3072 + s2 * 32 + (lane >> 4) * 8);
  }
  float l[4];
  f32x4 acc[4] = {};
  #pragma unroll
  for (int r = 0; r < 4; r++) l[r] = 0.f;

  const int NT = SS / KVBLK;

  int ksrc[2], vsrc[2];
  #pragma unroll
  for (int i = 0; i < 2; i++) {
    int idx = wid * 128 + i * 64 + lane;
    int R = idx >> 3, c = idx & 7;
    int key = (R & 15) * 4 + (R >> 4);
    ksrc[i] = key * 3072 + ((c ^ (R & 7)) * 8);
    vsrc[i] = R * SS + ((c ^ (R & 7)) * 8);
  }
  const int ldsb = wid * 1024;

  auto stageKV = [&](int buf, int t) {
    size_t kvK = (size_t)t * KVBLK * 3072;
    int kvV = t * KVBLK;
    gload_lds16(Kp + kvK + ksrc[0], &Kl[buf][ldsb]);
    gload_lds16(Kp + kvK + ksrc[1], &Kl[buf][ldsb + 512]);
    gload_lds16(Vg + kvV + vsrc[0], &Vl[buf][ldsb]);
    gload_lds16(Vg + kvV + vsrc[1], &Vl[buf][ldsb + 512]);
  };

  auto body = [&](int t, int cb) {
    __syncthreads();
    if (t + 1 < NT) stageKV(cb ^ 1, t + 1);

    f32x4 s4[4] = {};
    #pragma unroll
    for (int g = 0; g < 4; g++) {
      const ushort_t* kr = &Kl[cb][(g * 16 + (lane & 15)) * 64];
      bf16x8 kf0 = *(const bf16x8*)(kr + (((lane >> 4)) ^ ((lane & 15) & 7)) * 8);
      bf16x8 kf1 = *(const bf16x8*)(kr + ((4 + (lane >> 4)) ^ ((lane & 15) & 7)) * 8);
      s4[g] = __builtin_amdgcn_mfma_f32_16x16x32_bf16(qf[0], kf0, s4[g], 0, 0, 0);
      s4[g] = __builtin_amdgcn_mfma_f32_16x16x32_bf16(qf[1], kf1, s4[g], 0, 0, 0);
    }
    const int qrow = (lane >> 4) * 4;
    const int cp = (lane & 15) >> 1, hf = (lane & 15) & 1;
    #pragma unroll
    for (int r = 0; r < 4; r++) {
      float p0 = __builtin_amdgcn_exp2f(s4[0][r]);
      float p1 = __builtin_amdgcn_exp2f(s4[1][r]);
      float p2 = __builtin_amdgcn_exp2f(s4[2][r]);
      float p3 = __builtin_amdgcn_exp2f(s4[3][r]);
      l[r] += (p0 + p1) + (p2 + p3);
      unsigned w0, w1;
      asm("v_cvt_pk_bf16_f32 %0, %1, %2" : "=v"(w0) : "v"(p0), "v"(p1));
      asm("v_cvt_pk_bf16_f32 %0, %1, %2" : "=v"(w1) : "v"(p2), "v"(p3));
      uint2 pw; pw.x = w0; pw.y = w1;
      int qq = qrow + r;
      *(uint2*)(&Pl[wid][qq * 64 + ((cp ^ (qq & 7)) * 8) + hf * 4]) = pw;
    }
    asm volatile("s_waitcnt lgkmcnt(0)" ::: "memory");
    __builtin_amdgcn_sched_barrier(0);
    bf16x8 pf[2];
    {
      int qq = lane & 15;
      #pragma unroll
      for (int ks = 0; ks < 2; ks++) {
        int c = ks * 4 + (lane >> 4);
        pf[ks] = *(const bf16x8*)(&Pl[wid][qq * 64 + ((c ^ (qq & 7)) * 8)]);
      }
    }
    #pragma unroll
    for (int f = 0; f < 4; f++) {
      int d = f * 16 + (lane & 15);
      #pragma unroll
      for (int ks = 0; ks < 2; ks++) {
        int chunk = (ks * 4 + (lane >> 4)) ^ (d & 7);
        bf16x8 vf = *(const bf16x8*)(&Vl[cb][d * 64 + chunk * 8]);
        acc[f] = __builtin_amdgcn_mfma_f32_16x16x32_bf16(pf[ks], vf, acc[f], 0, 0, 0);
      }
    }
  };

  stageKV(0, 0);
  for (int t = 0; t < NT; t += 2) {
    body(t, 0);
    body(t + 1, 1);
  }

  #pragma unroll
  for (int r = 0; r < 4; r++) l[r] = dpp_sum16(l[r]);
  float rl4[4];
  #pragma unroll
  for (int r = 0; r < 4; r++) rl4[r] = 1.0f / l[r];
  #pragma unroll
  for (int f = 0; f < 4; f++)
    #pragma unroll
    for (int r = 0; r < 4; r++) {
      int row = b * SS + q0 + (lane >> 4) * 4 + r;
      int col = h * 64 + f * 16 + (lane & 15);
      ctx[(size_t)row * D_MODEL + col] = f2bf(acc[f][r] * rl4[r]);
    }
}

extern "C" void kernel_launch(void* const* d_in, const int* in_sizes, int n_in,
                              void* d_out, int out_size, void* d_ws, size_t ws_size,
                              hipStream_t stream) {
  const float* x    = (const float*)d_in[0];
  const float* ln1w = (const float*)d_in[1];
  const float* ln1b = (const float*)d_in[2];
  const float* Wq   = (const float*)d_in[3];
  const float* bq   = (const float*)d_in[4];
  const float* Wk   = (const float*)d_in[5];
  const float* bk   = (const float*)d_in[6];
  const float* Wv   = (const float*)d_in[7];
  const float* bv   = (const float*)d_in[8];
  const float* Wo   = (const float*)d_in[9];
  const float* bo   = (const float*)d_in[10];
  const float* ln2w = (const float*)d_in[11];
  const float* ln2b = (const float*)d_in[12];
  const float* W1   = (const float*)d_in[13];
  const float* b1   = (const float*)d_in[14];
  const float* W2   = (const float*)d_in[15];
  const float* b2   = (const float*)d_in[16];

  char* ws = (char*)d_ws;
  size_t off = 0;
  auto alloc = [&](size_t bytes) {
    void* p = ws + off;
    off += (bytes + 255) & ~(size_t)255;
    return p;
  };
  ushort_t* Wt_qkv = (ushort_t*)alloc((size_t)3072 * 1024 * 2);
  ushort_t* Wt_o   = (ushort_t*)alloc((size_t)1024 * 1024 * 2);
  ushort_t* Wt_1   = (ushort_t*)alloc((size_t)4096 * 1024 * 2);
  ushort_t* Wt_2   = (ushort_t*)alloc((size_t)1024 * 4096 * 2);
  float*    bqkv   = (float*)alloc((size_t)3072 * 4);
  ushort_t* qkvb   = (ushort_t*)alloc((size_t)MROWS * 3072 * 2);  // 24 MB
  ushort_t* ctxb   = (ushort_t*)alloc((size_t)MROWS * 1024 * 2);  // 8 MB
  ushort_t* hbuf   = (ushort_t*)alloc((size_t)MROWS * 1024 * 2);
  float*    x2     = (float*)alloc((size_t)MROWS * 1024 * 4);
  ushort_t* Vtb    = (ushort_t*)alloc((size_t)BB * NH * 64 * SS * 2);  // 8 MB
  ushort_t* ff1    = qkvb;  // reuse qkv(24MB)+ctx(8MB) = 32MB for [4096][4096] bf16
  float*    outp   = (float*)d_out;

  // split-K=2 partials for FFN2 (32 MB); fallback to fused if no room
  const size_t partial1 = (size_t)MROWS * 1024 * 4;  // 16 MB per split
  int S = (ws_size - off >= 2 * partial1 + 256) ? 2 : 1;
  float* pbuf = (S == 2) ? (float*)alloc(2 * partial1) : nullptr;

  dim3 tb(32, 8);
  transpose_cast_kernel<<<dim3(32, 32), tb, 0, stream>>>(Wq, Wt_qkv, 1024, 1024);
  transpose_cast_kernel<<<dim3(32, 32), tb, 0, stream>>>(Wk, Wt_qkv + 1024 * 1024, 1024, 1024);
  transpose_cast_kernel<<<dim3(32, 32), tb, 0, stream>>>(Wv, Wt_qkv + 2 * 1024 * 1024, 1024, 1024);
  transpose_cast_kernel<<<dim3(32, 32), tb, 0, stream>>>(Wo, Wt_o, 1024, 1024);
  transpose_cast_kernel<<<dim3(128, 32), tb, 0, stream>>>(W1, Wt_1, 1024, 4096);
  transpose_cast_kernel<<<dim3(32, 128), tb, 0, stream>>>(W2, Wt_2, 4096, 1024);
  hipMemcpyAsync(bqkv,        bq, 1024 * 4, hipMemcpyDeviceToDevice, stream);
  hipMemcpyAsync(bqkv + 1024, bk, 1024 * 4, hipMemcpyDeviceToDevice, stream);
  hipMemcpyAsync(bqkv + 2048, bv, 1024 * 4, hipMemcpyDeviceToDevice, stream);

  // LN1 -> h
  ln_bf16_kernel<<<MROWS, 256, 0, stream>>>(x, ln1w, ln1b, hbuf);
  // fused QKV GEMM: [4096,1024]x[1024,3072] -> bf16 (Q cols pre-scaled by Cs)
  gemm128_kernel<0><<<dim3(24 * 32), 256, 0, stream>>>(
      hbuf, Wt_qkv, bqkv, nullptr, qkvb, MROWS, 3072, 1024, 24, 1024, 24 * 32);
  // V transpose -> Vt[bh][64][2048]
  vtrans_kernel<<<dim3(SS / 64, BB * NH), 256, 0, stream>>>(qkvb, Vtb);
  // attention
  attn_kernel<<<dim3(SS / 64, BB * NH), 256, 0, stream>>>(qkvb, Vtb, ctxb);
  // O-proj + bias + residual(x) -> x2 (fp32), fused
  gemm128_kernel<2><<<dim3(8 * 32), 256, 0, stream>>>(
      ctxb, Wt_o, bo, x, x2, MROWS, 1024, 1024, 8, 1024, 8 * 32);
  // LN2 -> h
  ln_bf16_kernel<<<MROWS, 256, 0, stream>>>(x2, ln2w, ln2b, hbuf);
  // FFN1 + relu -> ff1 (bf16)
  gemm128_kernel<1><<<dim3(32 * 32), 256, 0, stream>>>(
      hbuf, Wt_1, b1, nullptr, ff1, MROWS, D_FF, 1024, 32, 1024, 32 * 32);
  // FFN2: split-K=2 -> fp32 partials; reduce adds bias b2 + resid x2 -> out
  if (S == 2) {
    gemm128_kernel<3><<<dim3(8 * 32 * 2), 256, 0, stream>>>(
        ff1, Wt_2, nullptr, nullptr, pbuf, MROWS, 1024, 4096, 8, 2048, 8 * 32);
    reduce_kernel<<<2048, 256, 0, stream>>>(pbuf, b2, x2, outp, 2,
        (size_t)MROWS * 1024 / 4, (size_t)MROWS * 1024 / 4);
  } else {
    gemm128_kernel<2><<<dim3(8 * 32), 256, 0, stream>>>(
        ff1, Wt_2, b2, x2, outp, MROWS, 1024, 4096, 8, 4096, 8 * 32);
  }
}

// Round 11
// 249.732 us; speedup vs baseline: 1.0794x; 1.0153x over previous
//
#include <hip/hip_runtime.h>
#include <hip/hip_bf16.h>
#include <cstdint>
#include <cstddef>

typedef unsigned short ushort_t;
typedef __bf16 bf16x8 __attribute__((ext_vector_type(8)));
typedef float f32x4 __attribute__((ext_vector_type(4)));

#define D_MODEL 1024
#define D_FF 4096
#define BB 2
#define SS 2048
#define NH 16
#define MROWS (BB * SS) /* 4096 */
#define KVBLK 64

__device__ __forceinline__ ushort_t f2bf(float f) {
  union { float f; unsigned u; } x; x.f = f;
  unsigned r = x.u + 0x7fffu + ((x.u >> 16) & 1u);
  return (ushort_t)(r >> 16);
}

__device__ __forceinline__ void gload_lds16(const void* g, void* l) {
  __builtin_amdgcn_global_load_lds((const __attribute__((address_space(1))) void*)g,
                                   (__attribute__((address_space(3))) void*)l, 16, 0, 0);
}

__device__ __forceinline__ float dpp_sum16(float x) {
  int v;
  v = __builtin_amdgcn_update_dpp(0, __float_as_int(x), 0xB1, 0xF, 0xF, true);
  x += __int_as_float(v);
  v = __builtin_amdgcn_update_dpp(0, __float_as_int(x), 0x4E, 0xF, 0xF, true);
  x += __int_as_float(v);
  v = __builtin_amdgcn_update_dpp(0, __float_as_int(x), 0x141, 0xF, 0xF, true);
  x += __int_as_float(v);
  v = __builtin_amdgcn_update_dpp(0, __float_as_int(x), 0x140, 0xF, 0xF, true);
  x += __int_as_float(v);
  return x;
}

// ---------------- LayerNorm (fp32 in -> bf16 out) ----------------
__global__ __launch_bounds__(256) void ln_bf16_kernel(
    const float* __restrict__ x, const float* __restrict__ w,
    const float* __restrict__ b, ushort_t* __restrict__ out) {
  int row = blockIdx.x;
  int tid = threadIdx.x;
  int lane = tid & 63, wid = tid >> 6;
  const float4 v = ((const float4*)(x + (size_t)row * D_MODEL))[tid];
  float s = v.x + v.y + v.z + v.w;
  __shared__ float red[8];
  #pragma unroll
  for (int o = 32; o > 0; o >>= 1) s += __shfl_down(s, o);
  if (lane == 0) red[wid] = s;
  __syncthreads();
  float mu = (red[0] + red[1] + red[2] + red[3]) * (1.0f / D_MODEL);
  float d0 = v.x - mu, d1 = v.y - mu, d2 = v.z - mu, d3 = v.w - mu;
  float sq = d0 * d0 + d1 * d1 + d2 * d2 + d3 * d3;
  #pragma unroll
  for (int o = 32; o > 0; o >>= 1) sq += __shfl_down(sq, o);
  if (lane == 0) red[4 + wid] = sq;
  __syncthreads();
  float var = (red[4] + red[5] + red[6] + red[7]) * (1.0f / D_MODEL);
  float rstd = rsqrtf(var + 1e-5f);
  const float4 wv = ((const float4*)w)[tid];
  const float4 bv = ((const float4*)b)[tid];
  ushort4 o4;
  o4.x = f2bf(d0 * rstd * wv.x + bv.x);
  o4.y = f2bf(d1 * rstd * wv.y + bv.y);
  o4.z = f2bf(d2 * rstd * wv.z + bv.z);
  o4.w = f2bf(d3 * rstd * wv.w + bv.w);
  ((ushort4*)(out + (size_t)row * D_MODEL))[tid] = o4;
}

// ---------------- transpose + cast: W[K][N] fp32 -> Wt[N][K] bf16 ----------------
__global__ __launch_bounds__(256) void transpose_cast_kernel(
    const float* __restrict__ W, ushort_t* __restrict__ Wt, int K, int N) {
  __shared__ float tile[32][33];
  int bx = blockIdx.x * 32;  // n
  int by = blockIdx.y * 32;  // k
  int tx = threadIdx.x, ty = threadIdx.y;  // 32 x 8
  #pragma unroll
  for (int i = 0; i < 32; i += 8)
    tile[ty + i][tx] = W[(size_t)(by + ty + i) * N + bx + tx];
  __syncthreads();
  #pragma unroll
  for (int i = 0; i < 32; i += 8)
    Wt[(size_t)(bx + ty + i) * K + by + tx] = f2bf(tile[tx][ty + i]);
}

// ---------------- V transpose: qkv V-slice -> Vt[bh][64 d][SS keys] bf16 ----------------
__global__ __launch_bounds__(256) void vtrans_kernel(
    const ushort_t* __restrict__ qkv, ushort_t* __restrict__ Vt) {
  __shared__ __align__(16) ushort_t T[64 * 64];  // [key][d], chunk-XOR swizzled
  const int tid = threadIdx.x;
  const int bh = blockIdx.y, b = bh >> 4, h = bh & 15;
  const int kv0 = blockIdx.x * 64;
  const ushort_t* Vp = qkv + (size_t)b * SS * 3072 + 2048 + h * 64;
  #pragma unroll
  for (int i = 0; i < 2; i++) {
    int idx = tid * 2 + i;          // chunk index
    int key = idx >> 3, c = idx & 7;
    bf16x8 v = *(const bf16x8*)(Vp + (size_t)(kv0 + key) * 3072 + c * 8);
    *(bf16x8*)(T + key * 64 + ((c ^ (key & 7)) * 8)) = v;
  }
  __syncthreads();
  int d = tid >> 2, kb = tid & 3;
  ushort_t o[16];
  #pragma unroll
  for (int j = 0; j < 16; j++) {
    int key = kb * 16 + j;
    o[j] = T[key * 64 + (((d >> 3) ^ (key & 7)) * 8) + (d & 7)];
  }
  ushort_t* dst = Vt + (size_t)(bh * 64 + d) * SS + kv0 + kb * 16;
  *(bf16x8*)dst = *(bf16x8*)&o[0];
  *(bf16x8*)(dst + 8) = *(bf16x8*)&o[8];
}

// ---------------- GEMM 128x128, BK=32, 4-deep LDS pipeline, counted vmcnt ----------------
// EPI: 0 = bf16 + bias (cols<1024 scaled by Cs for QKV); 1 = bf16 + bias + relu;
//      2 = fp32 + bias + resid (fused); 3 = fp32 partial at Cout + s*M*N (split-K).
template <int EPI>
__global__ __launch_bounds__(256, 2) void gemm128_kernel(
    const ushort_t* __restrict__ A, const ushort_t* __restrict__ Bt,
    const float* __restrict__ bias, const float* __restrict__ resid,
    void* __restrict__ Cout, int M, int N, int K, int NTn, int Ksplit, int MTN) {
  __shared__ __align__(16) ushort_t lds[4][2][4096];  // [buf][A|B][8KB]
  const int tid = threadIdx.x, lane = tid & 63, wid = tid >> 6;
  const int wm = wid >> 1, wn = wid & 1;
  const int rl = lane & 15, cg = lane >> 4;
  int nwg = gridDim.x;
  int q = nwg >> 3, rr = nwg & 7;
  int xcd = blockIdx.x & 7, idx = blockIdx.x >> 3;
  int wgid = (xcd < rr ? xcd * (q + 1) : rr * (q + 1) + (xcd - rr) * q) + idx;
  const int s = wgid / MTN;
  int rem = wgid - s * MTN;
  const int row0 = (rem / NTn) * 128, col0 = (rem - (rem / NTn) * NTn) * 128;
  const int k0 = s * Ksplit;
  const int NT = Ksplit / 32;

  int soff[2], ldso[2];
  #pragma unroll
  for (int i = 0; i < 2; i++) {
    int ci = wid * 128 + i * 64 + lane;
    int P = ci * 16;
    int L = P ^ (((P >> 7) & 7) << 4);
    int row = L >> 6, kc = (L >> 4) & 3;
    soff[i] = row * K + kc * 8;
    ldso[i] = (wid * 128 + i * 64) * 8;
  }

  f32x4 acc[4][4] = {};

  auto stage = [&](int t) {
    int b = t & 3;
    int kk = k0 + t * 32;
    #pragma unroll
    for (int i = 0; i < 2; i++) {
      gload_lds16(A + (size_t)row0 * K + kk + soff[i], &lds[b][0][ldso[i]]);
      gload_lds16(Bt + (size_t)col0 * K + kk + soff[i], &lds[b][1][ldso[i]]);
    }
  };

  auto compute = [&](int t) {
    int b = t & 3;
    bf16x8 af[4], bfv[4];
    #pragma unroll
    for (int mi = 0; mi < 4; mi++) {
      int r = wm * 64 + mi * 16 + rl;
      int L = r * 64 + cg * 16;
      int P = L ^ (((L >> 7) & 7) << 4);
      af[mi] = *(const bf16x8*)&lds[b][0][P >> 1];
    }
    #pragma unroll
    for (int ni = 0; ni < 4; ni++) {
      int r = wn * 64 + ni * 16 + rl;
      int L = r * 64 + cg * 16;
      int P = L ^ (((L >> 7) & 7) << 4);
      bfv[ni] = *(const bf16x8*)&lds[b][1][P >> 1];
    }
    __builtin_amdgcn_s_setprio(1);
    #pragma unroll
    for (int mi = 0; mi < 4; mi++)
      #pragma unroll
      for (int ni = 0; ni < 4; ni++)
        acc[mi][ni] = __builtin_amdgcn_mfma_f32_16x16x32_bf16(af[mi], bfv[ni], acc[mi][ni], 0, 0, 0);
    __builtin_amdgcn_s_setprio(0);
  };

  stage(0); stage(1); stage(2);
  for (int t = 0; t < NT; ++t) {
    if (t < NT - 2)       asm volatile("s_waitcnt vmcnt(8)" ::: "memory");
    else if (t == NT - 2) asm volatile("s_waitcnt vmcnt(4)" ::: "memory");
    else                  asm volatile("s_waitcnt vmcnt(0)" ::: "memory");
    __builtin_amdgcn_s_barrier();
    __builtin_amdgcn_sched_barrier(0);
    if (t + 3 < NT) stage(t + 3);
    compute(t);
  }

  if (EPI == 2) {
    float* out = (float*)Cout;
    #pragma unroll
    for (int ni = 0; ni < 4; ni++) {
      int col = col0 + wn * 64 + ni * 16 + rl;
      float bv = bias[col];
      #pragma unroll
      for (int mi = 0; mi < 4; mi++) {
        int rowb = row0 + wm * 64 + mi * 16 + cg * 4;
        #pragma unroll
        for (int j = 0; j < 4; j++)
          out[(size_t)(rowb + j) * N + col] =
              acc[mi][ni][j] + bv + resid[(size_t)(rowb + j) * N + col];
      }
    }
  } else if (EPI == 3) {
    float* out = (float*)Cout + (size_t)s * M * N;
    #pragma unroll
    for (int ni = 0; ni < 4; ni++) {
      int col = col0 + wn * 64 + ni * 16 + rl;
      #pragma unroll
      for (int mi = 0; mi < 4; mi++) {
        int rowb = row0 + wm * 64 + mi * 16 + cg * 4;
        #pragma unroll
        for (int j = 0; j < 4; j++)
          out[(size_t)(rowb + j) * N + col] = acc[mi][ni][j];
      }
    }
  } else {
    ushort_t* out = (ushort_t*)Cout;
    #pragma unroll
    for (int ni = 0; ni < 4; ni++) {
      int col = col0 + wn * 64 + ni * 16 + rl;
      float bv = bias[col];
      float sc = (EPI == 0 && col < 1024) ? 0.18033688011f : 1.0f;
      #pragma unroll
      for (int mi = 0; mi < 4; mi++) {
        int rowb = row0 + wm * 64 + mi * 16 + cg * 4;
        #pragma unroll
        for (int j = 0; j < 4; j++) {
          float v = acc[mi][ni][j] + bv;
          if (EPI == 1) v = fmaxf(v, 0.0f);
          if (EPI == 0) v *= sc;
          out[(size_t)(rowb + j) * N + col] = f2bf(v);
        }
      }
    }
  }
}

// ---------------- split-K reduce: out = sum(partials) + bias + resid (fp32, N=1024) ----------------
__global__ __launch_bounds__(256) void reduce_kernel(
    const float* __restrict__ p, const float* __restrict__ bias,
    const float* __restrict__ resid, float* __restrict__ out,
    int S, size_t total4, size_t stride4) {
  const float4* p4 = (const float4*)p;
  const float4* r4 = (const float4*)resid;
  const float4* b4 = (const float4*)bias;
  float4* o4 = (float4*)out;
  for (size_t i = (size_t)blockIdx.x * 256 + threadIdx.x; i < total4;
       i += (size_t)gridDim.x * 256) {
    float4 a = r4[i];
    float4 bb = b4[i & 255];
    a.x += bb.x; a.y += bb.y; a.z += bb.z; a.w += bb.w;
    for (int s = 0; s < S; ++s) {
      float4 v = p4[(size_t)s * stride4 + i];
      a.x += v.x; a.y += v.y; a.z += v.z; a.w += v.w;
    }
    o4[i] = a;
  }
}

// ---------------- flash attention: 128 q/block (32 q/wave), K+V LDS dbuf ----------------
// Static-shift softmax (Q pre-scaled by Cs in QKV epilogue; exp2 overflow-safe by C-S bound).
// 32 q/wave doubles MFMA per LDS byte: 8 K-reads feed 16 QK MFMAs, 8 V-reads feed 16 PV.
__global__ __launch_bounds__(256) void attn_kernel(
    const ushort_t* __restrict__ qkv, const ushort_t* __restrict__ Vt,
    ushort_t* __restrict__ ctx) {
  __shared__ __align__(16) ushort_t Kl[2][64 * 64];   // 8KB each
  __shared__ __align__(16) ushort_t Vl[2][64 * 64];   // 8KB each
  __shared__ __align__(16) ushort_t Pl[4][32 * 64];   // 4KB per wave
  const int tid = threadIdx.x, lane = tid & 63, wid = tid >> 6;
  // XCD swizzle over 512 wgs (16 q-tiles x 32 bh)
  int bid = blockIdx.y * 16 + blockIdx.x;
  int w = (bid & 7) * 64 + (bid >> 3);
  const int bh = w >> 4, qt = w & 15;
  const int b = bh >> 4, h = bh & 15;
  const int q0 = qt * 128 + wid * 32;
  const ushort_t* Qp = qkv + (size_t)b * SS * 3072 + h * 64;
  const ushort_t* Kp = Qp + 1024;
  const ushort_t* Vg = Vt + (size_t)bh * 64 * SS;

  bf16x8 qf[2][2];
  #pragma unroll
  for (int mi = 0; mi < 2; mi++) {
    int qr = q0 + mi * 16 + (lane & 15);
    #pragma unroll
    for (int s2 = 0; s2 < 2; s2++)
      qf[mi][s2] = *(const bf16x8*)(Qp + (size_t)qr * 3072 + s2 * 32 + (lane >> 4) * 8);
  }
  float l[2][4];
  f32x4 acc[2][4] = {};
  #pragma unroll
  for (int mi = 0; mi < 2; mi++)
    #pragma unroll
    for (int r = 0; r < 4; r++) l[mi][r] = 0.f;

  const int NT = SS / KVBLK;

  int ksrc[2], vsrc[2];
  #pragma unroll
  for (int i = 0; i < 2; i++) {
    int idx = wid * 128 + i * 64 + lane;
    int R = idx >> 3, c = idx & 7;
    int key = (R & 15) * 4 + (R >> 4);
    ksrc[i] = key * 3072 + ((c ^ (R & 7)) * 8);
    vsrc[i] = R * SS + ((c ^ (R & 7)) * 8);
  }
  const int ldsb = wid * 1024;

  auto stageKV = [&](int buf, int t) {
    size_t kvK = (size_t)t * KVBLK * 3072;
    int kvV = t * KVBLK;
    gload_lds16(Kp + kvK + ksrc[0], &Kl[buf][ldsb]);
    gload_lds16(Kp + kvK + ksrc[1], &Kl[buf][ldsb + 512]);
    gload_lds16(Vg + kvV + vsrc[0], &Vl[buf][ldsb]);
    gload_lds16(Vg + kvV + vsrc[1], &Vl[buf][ldsb + 512]);
  };

  auto body = [&](int t, int cb) {
    __syncthreads();
    if (t + 1 < NT) stageKV(cb ^ 1, t + 1);

    // QK^T: s4[mi][g][r] = S[q0 + mi*16 + (lane>>4)*4 + r][kv + (lane&15)*4 + g]
    f32x4 s4[2][4] = {};
    #pragma unroll
    for (int g = 0; g < 4; g++) {
      const ushort_t* kr = &Kl[cb][(g * 16 + (lane & 15)) * 64];
      bf16x8 kf0 = *(const bf16x8*)(kr + (((lane >> 4)) ^ ((lane & 15) & 7)) * 8);
      bf16x8 kf1 = *(const bf16x8*)(kr + ((4 + (lane >> 4)) ^ ((lane & 15) & 7)) * 8);
      #pragma unroll
      for (int mi = 0; mi < 2; mi++) {
        s4[mi][g] = __builtin_amdgcn_mfma_f32_16x16x32_bf16(qf[mi][0], kf0, s4[mi][g], 0, 0, 0);
        s4[mi][g] = __builtin_amdgcn_mfma_f32_16x16x32_bf16(qf[mi][1], kf1, s4[mi][g], 0, 0, 0);
      }
    }
    const int cp = (lane & 15) >> 1, hf = (lane & 15) & 1;
    #pragma unroll
    for (int mi = 0; mi < 2; mi++) {
      const int qrow = mi * 16 + (lane >> 4) * 4;
      #pragma unroll
      for (int r = 0; r < 4; r++) {
        float p0 = __builtin_amdgcn_exp2f(s4[mi][0][r]);
        float p1 = __builtin_amdgcn_exp2f(s4[mi][1][r]);
        float p2 = __builtin_amdgcn_exp2f(s4[mi][2][r]);
        float p3 = __builtin_amdgcn_exp2f(s4[mi][3][r]);
        l[mi][r] += (p0 + p1) + (p2 + p3);
        unsigned w0, w1;
        asm("v_cvt_pk_bf16_f32 %0, %1, %2" : "=v"(w0) : "v"(p0), "v"(p1));
        asm("v_cvt_pk_bf16_f32 %0, %1, %2" : "=v"(w1) : "v"(p2), "v"(p3));
        uint2 pw; pw.x = w0; pw.y = w1;
        int qq = qrow + r;
        *(uint2*)(&Pl[wid][qq * 64 + ((cp ^ (qq & 7)) * 8) + hf * 4]) = pw;
      }
    }
    asm volatile("s_waitcnt lgkmcnt(0)" ::: "memory");
    __builtin_amdgcn_sched_barrier(0);
    bf16x8 pf[2][2];
    #pragma unroll
    for (int mi = 0; mi < 2; mi++) {
      int qq = mi * 16 + (lane & 15);
      #pragma unroll
      for (int ks = 0; ks < 2; ks++) {
        int c = ks * 4 + (lane >> 4);
        pf[mi][ks] = *(const bf16x8*)(&Pl[wid][qq * 64 + ((c ^ (qq & 7)) * 8)]);
      }
    }
    #pragma unroll
    for (int f = 0; f < 4; f++) {
      int d = f * 16 + (lane & 15);
      #pragma unroll
      for (int ks = 0; ks < 2; ks++) {
        int chunk = (ks * 4 + (lane >> 4)) ^ (d & 7);
        bf16x8 vf = *(const bf16x8*)(&Vl[cb][d * 64 + chunk * 8]);
        #pragma unroll
        for (int mi = 0; mi < 2; mi++)
          acc[mi][f] = __builtin_amdgcn_mfma_f32_16x16x32_bf16(pf[mi][ks], vf, acc[mi][f], 0, 0, 0);
      }
    }
  };

  stageKV(0, 0);
  for (int t = 0; t < NT; t += 2) {
    body(t, 0);
    body(t + 1, 1);
  }

  float rl4[2][4];
  #pragma unroll
  for (int mi = 0; mi < 2; mi++)
    #pragma unroll
    for (int r = 0; r < 4; r++) rl4[mi][r] = 1.0f / dpp_sum16(l[mi][r]);
  #pragma unroll
  for (int mi = 0; mi < 2; mi++)
    #pragma unroll
    for (int f = 0; f < 4; f++)
      #pragma unroll
      for (int r = 0; r < 4; r++) {
        int row = b * SS + q0 + mi * 16 + (lane >> 4) * 4 + r;
        int col = h * 64 + f * 16 + (lane & 15);
        ctx[(size_t)row * D_MODEL + col] = f2bf(acc[mi][f][r] * rl4[mi][r]);
      }
}

extern "C" void kernel_launch(void* const* d_in, const int* in_sizes, int n_in,
                              void* d_out, int out_size, void* d_ws, size_t ws_size,
                              hipStream_t stream) {
  const float* x    = (const float*)d_in[0];
  const float* ln1w = (const float*)d_in[1];
  const float* ln1b = (const float*)d_in[2];
  const float* Wq   = (const float*)d_in[3];
  const float* bq   = (const float*)d_in[4];
  const float* Wk   = (const float*)d_in[5];
  const float* bk   = (const float*)d_in[6];
  const float* Wv   = (const float*)d_in[7];
  const float* bv   = (const float*)d_in[8];
  const float* Wo   = (const float*)d_in[9];
  const float* bo   = (const float*)d_in[10];
  const float* ln2w = (const float*)d_in[11];
  const float* ln2b = (const float*)d_in[12];
  const float* W1   = (const float*)d_in[13];
  const float* b1   = (const float*)d_in[14];
  const float* W2   = (const float*)d_in[15];
  const float* b2   = (const float*)d_in[16];

  char* ws = (char*)d_ws;
  size_t off = 0;
  auto alloc = [&](size_t bytes) {
    void* p = ws + off;
    off += (bytes + 255) & ~(size_t)255;
    return p;
  };
  ushort_t* Wt_qkv = (ushort_t*)alloc((size_t)3072 * 1024 * 2);
  ushort_t* Wt_o   = (ushort_t*)alloc((size_t)1024 * 1024 * 2);
  ushort_t* Wt_1   = (ushort_t*)alloc((size_t)4096 * 1024 * 2);
  ushort_t* Wt_2   = (ushort_t*)alloc((size_t)1024 * 4096 * 2);
  float*    bqkv   = (float*)alloc((size_t)3072 * 4);
  ushort_t* qkvb   = (ushort_t*)alloc((size_t)MROWS * 3072 * 2);  // 24 MB
  ushort_t* ctxb   = (ushort_t*)alloc((size_t)MROWS * 1024 * 2);  // 8 MB
  ushort_t* hbuf   = (ushort_t*)alloc((size_t)MROWS * 1024 * 2);
  float*    x2     = (float*)alloc((size_t)MROWS * 1024 * 4);
  ushort_t* Vtb    = (ushort_t*)alloc((size_t)BB * NH * 64 * SS * 2);  // 8 MB
  ushort_t* ff1    = qkvb;  // reuse qkv(24MB)+ctx(8MB) = 32MB for [4096][4096] bf16
  float*    outp   = (float*)d_out;

  // split-K=2 partials for FFN2 (32 MB); fallback to fused if no room
  const size_t partial1 = (size_t)MROWS * 1024 * 4;  // 16 MB per split
  int S = (ws_size - off >= 2 * partial1 + 256) ? 2 : 1;
  float* pbuf = (S == 2) ? (float*)alloc(2 * partial1) : nullptr;

  dim3 tb(32, 8);
  transpose_cast_kernel<<<dim3(32, 32), tb, 0, stream>>>(Wq, Wt_qkv, 1024, 1024);
  transpose_cast_kernel<<<dim3(32, 32), tb, 0, stream>>>(Wk, Wt_qkv + 1024 * 1024, 1024, 1024);
  transpose_cast_kernel<<<dim3(32, 32), tb, 0, stream>>>(Wv, Wt_qkv + 2 * 1024 * 1024, 1024, 1024);
  transpose_cast_kernel<<<dim3(32, 32), tb, 0, stream>>>(Wo, Wt_o, 1024, 1024);
  transpose_cast_kernel<<<dim3(128, 32), tb, 0, stream>>>(W1, Wt_1, 1024, 4096);
  transpose_cast_kernel<<<dim3(32, 128), tb, 0, stream>>>(W2, Wt_2, 4096, 1024);
  hipMemcpyAsync(bqkv,        bq, 1024 * 4, hipMemcpyDeviceToDevice, stream);
  hipMemcpyAsync(bqkv + 1024, bk, 1024 * 4, hipMemcpyDeviceToDevice, stream);
  hipMemcpyAsync(bqkv + 2048, bv, 1024 * 4, hipMemcpyDeviceToDevice, stream);

  // LN1 -> h
  ln_bf16_kernel<<<MROWS, 256, 0, stream>>>(x, ln1w, ln1b, hbuf);
  // fused QKV GEMM: [4096,1024]x[1024,3072] -> bf16 (Q cols pre-scaled by Cs)
  gemm128_kernel<0><<<dim3(24 * 32), 256, 0, stream>>>(
      hbuf, Wt_qkv, bqkv, nullptr, qkvb, MROWS, 3072, 1024, 24, 1024, 24 * 32);
  // V transpose -> Vt[bh][64][2048]
  vtrans_kernel<<<dim3(SS / 64, BB * NH), 256, 0, stream>>>(qkvb, Vtb);
  // attention: 128 q/block, 512 blocks
  attn_kernel<<<dim3(SS / 128, BB * NH), 256, 0, stream>>>(qkvb, Vtb, ctxb);
  // O-proj + bias + residual(x) -> x2 (fp32), fused
  gemm128_kernel<2><<<dim3(8 * 32), 256, 0, stream>>>(
      ctxb, Wt_o, bo, x, x2, MROWS, 1024, 1024, 8, 1024, 8 * 32);
  // LN2 -> h
  ln_bf16_kernel<<<MROWS, 256, 0, stream>>>(x2, ln2w, ln2b, hbuf);
  // FFN1 + relu -> ff1 (bf16)
  gemm128_kernel<1><<<dim3(32 * 32), 256, 0, stream>>>(
      hbuf, Wt_1, b1, nullptr, ff1, MROWS, D_FF, 1024, 32, 1024, 32 * 32);
  // FFN2: split-K=2 -> fp32 partials; reduce adds bias b2 + resid x2 -> out
  if (S == 2) {
    gemm128_kernel<3><<<dim3(8 * 32 * 2), 256, 0, stream>>>(
        ff1, Wt_2, nullptr, nullptr, pbuf, MROWS, 1024, 4096, 8, 2048, 8 * 32);
    reduce_kernel<<<2048, 256, 0, stream>>>(pbuf, b2, x2, outp, 2,
        (size_t)MROWS * 1024 / 4, (size_t)MROWS * 1024 / 4);
  } else {
    gemm128_kernel<2><<<dim3(8 * 32), 256, 0, stream>>>(
        ff1, Wt_2, b2, x2, outp, MROWS, 1024, 4096, 8, 4096, 8 * 32);
  }
}

// Round 12
// 246.129 us; speedup vs baseline: 1.0952x; 1.0146x over previous
//
#include <hip/hip_runtime.h>
#include <hip/hip_bf16.h>
#include <cstdint>
#include <cstddef>

typedef unsigned short ushort_t;
typedef __bf16 bf16x8 __attribute__((ext_vector_type(8)));
typedef float f32x4 __attribute__((ext_vector_type(4)));
typedef float f32x16 __attribute__((ext_vector_type(16)));

#define D_MODEL 1024
#define D_FF 4096
#define BB 2
#define SS 2048
#define NH 16
#define MROWS (BB * SS) /* 4096 */
#define KVBLK 64

__device__ __forceinline__ ushort_t f2bf(float f) {
  union { float f; unsigned u; } x; x.f = f;
  unsigned r = x.u + 0x7fffu + ((x.u >> 16) & 1u);
  return (ushort_t)(r >> 16);
}

__device__ __forceinline__ void gload_lds16(const void* g, void* l) {
  __builtin_amdgcn_global_load_lds((const __attribute__((address_space(1))) void*)g,
                                   (__attribute__((address_space(3))) void*)l, 16, 0, 0);
}

__device__ __forceinline__ bf16x8 pack4w(unsigned w0, unsigned w1, unsigned w2, unsigned w3) {
  union { unsigned u[4]; bf16x8 v; } t;
  t.u[0] = w0; t.u[1] = w1; t.u[2] = w2; t.u[3] = w3;
  return t.v;
}

// ---------------- LayerNorm (fp32 in -> bf16 out) ----------------
__global__ __launch_bounds__(256) void ln_bf16_kernel(
    const float* __restrict__ x, const float* __restrict__ w,
    const float* __restrict__ b, ushort_t* __restrict__ out) {
  int row = blockIdx.x;
  int tid = threadIdx.x;
  int lane = tid & 63, wid = tid >> 6;
  const float4 v = ((const float4*)(x + (size_t)row * D_MODEL))[tid];
  float s = v.x + v.y + v.z + v.w;
  __shared__ float red[8];
  #pragma unroll
  for (int o = 32; o > 0; o >>= 1) s += __shfl_down(s, o);
  if (lane == 0) red[wid] = s;
  __syncthreads();
  float mu = (red[0] + red[1] + red[2] + red[3]) * (1.0f / D_MODEL);
  float d0 = v.x - mu, d1 = v.y - mu, d2 = v.z - mu, d3 = v.w - mu;
  float sq = d0 * d0 + d1 * d1 + d2 * d2 + d3 * d3;
  #pragma unroll
  for (int o = 32; o > 0; o >>= 1) sq += __shfl_down(sq, o);
  if (lane == 0) red[4 + wid] = sq;
  __syncthreads();
  float var = (red[4] + red[5] + red[6] + red[7]) * (1.0f / D_MODEL);
  float rstd = rsqrtf(var + 1e-5f);
  const float4 wv = ((const float4*)w)[tid];
  const float4 bv = ((const float4*)b)[tid];
  ushort4 o4;
  o4.x = f2bf(d0 * rstd * wv.x + bv.x);
  o4.y = f2bf(d1 * rstd * wv.y + bv.y);
  o4.z = f2bf(d2 * rstd * wv.z + bv.z);
  o4.w = f2bf(d3 * rstd * wv.w + bv.w);
  ((ushort4*)(out + (size_t)row * D_MODEL))[tid] = o4;
}

// ---------------- transpose + cast: W[K][N] fp32 -> Wt[N][K] bf16 ----------------
__global__ __launch_bounds__(256) void transpose_cast_kernel(
    const float* __restrict__ W, ushort_t* __restrict__ Wt, int K, int N) {
  __shared__ float tile[32][33];
  int bx = blockIdx.x * 32;  // n
  int by = blockIdx.y * 32;  // k
  int tx = threadIdx.x, ty = threadIdx.y;  // 32 x 8
  #pragma unroll
  for (int i = 0; i < 32; i += 8)
    tile[ty + i][tx] = W[(size_t)(by + ty + i) * N + bx + tx];
  __syncthreads();
  #pragma unroll
  for (int i = 0; i < 32; i += 8)
    Wt[(size_t)(bx + ty + i) * K + by + tx] = f2bf(tile[tx][ty + i]);
}

// ---------------- V transpose: qkv V-slice -> Vt[bh][64 d][SS keys] bf16 ----------------
__global__ __launch_bounds__(256) void vtrans_kernel(
    const ushort_t* __restrict__ qkv, ushort_t* __restrict__ Vt) {
  __shared__ __align__(16) ushort_t T[64 * 64];  // [key][d], chunk-XOR swizzled
  const int tid = threadIdx.x;
  const int bh = blockIdx.y, b = bh >> 4, h = bh & 15;
  const int kv0 = blockIdx.x * 64;
  const ushort_t* Vp = qkv + (size_t)b * SS * 3072 + 2048 + h * 64;
  #pragma unroll
  for (int i = 0; i < 2; i++) {
    int idx = tid * 2 + i;          // chunk index
    int key = idx >> 3, c = idx & 7;
    bf16x8 v = *(const bf16x8*)(Vp + (size_t)(kv0 + key) * 3072 + c * 8);
    *(bf16x8*)(T + key * 64 + ((c ^ (key & 7)) * 8)) = v;
  }
  __syncthreads();
  int d = tid >> 2, kb = tid & 3;
  ushort_t o[16];
  #pragma unroll
  for (int j = 0; j < 16; j++) {
    int key = kb * 16 + j;
    o[j] = T[key * 64 + (((d >> 3) ^ (key & 7)) * 8) + (d & 7)];
  }
  ushort_t* dst = Vt + (size_t)(bh * 64 + d) * SS + kv0 + kb * 16;
  *(bf16x8*)dst = *(bf16x8*)&o[0];
  *(bf16x8*)(dst + 8) = *(bf16x8*)&o[8];
}

// ---------------- GEMM 128x128, BK=32, 4-deep LDS pipeline, counted vmcnt ----------------
// EPI: 0 = bf16 + bias (cols<1024 scaled by Cs for QKV); 1 = bf16 + bias + relu;
//      2 = fp32 + bias + resid (fused); 3 = fp32 partial at Cout + s*M*N (split-K).
template <int EPI>
__global__ __launch_bounds__(256, 2) void gemm128_kernel(
    const ushort_t* __restrict__ A, const ushort_t* __restrict__ Bt,
    const float* __restrict__ bias, const float* __restrict__ resid,
    void* __restrict__ Cout, int M, int N, int K, int NTn, int Ksplit, int MTN) {
  __shared__ __align__(16) ushort_t lds[4][2][4096];  // [buf][A|B][8KB]
  const int tid = threadIdx.x, lane = tid & 63, wid = tid >> 6;
  const int wm = wid >> 1, wn = wid & 1;
  const int rl = lane & 15, cg = lane >> 4;
  int nwg = gridDim.x;
  int q = nwg >> 3, rr = nwg & 7;
  int xcd = blockIdx.x & 7, idx = blockIdx.x >> 3;
  int wgid = (xcd < rr ? xcd * (q + 1) : rr * (q + 1) + (xcd - rr) * q) + idx;
  const int s = wgid / MTN;
  int rem = wgid - s * MTN;
  const int row0 = (rem / NTn) * 128, col0 = (rem - (rem / NTn) * NTn) * 128;
  const int k0 = s * Ksplit;
  const int NT = Ksplit / 32;

  int soff[2], ldso[2];
  #pragma unroll
  for (int i = 0; i < 2; i++) {
    int ci = wid * 128 + i * 64 + lane;
    int P = ci * 16;
    int L = P ^ (((P >> 7) & 7) << 4);
    int row = L >> 6, kc = (L >> 4) & 3;
    soff[i] = row * K + kc * 8;
    ldso[i] = (wid * 128 + i * 64) * 8;
  }

  f32x4 acc[4][4] = {};

  auto stage = [&](int t) {
    int b = t & 3;
    int kk = k0 + t * 32;
    #pragma unroll
    for (int i = 0; i < 2; i++) {
      gload_lds16(A + (size_t)row0 * K + kk + soff[i], &lds[b][0][ldso[i]]);
      gload_lds16(Bt + (size_t)col0 * K + kk + soff[i], &lds[b][1][ldso[i]]);
    }
  };

  auto compute = [&](int t) {
    int b = t & 3;
    bf16x8 af[4], bfv[4];
    #pragma unroll
    for (int mi = 0; mi < 4; mi++) {
      int r = wm * 64 + mi * 16 + rl;
      int L = r * 64 + cg * 16;
      int P = L ^ (((L >> 7) & 7) << 4);
      af[mi] = *(const bf16x8*)&lds[b][0][P >> 1];
    }
    #pragma unroll
    for (int ni = 0; ni < 4; ni++) {
      int r = wn * 64 + ni * 16 + rl;
      int L = r * 64 + cg * 16;
      int P = L ^ (((L >> 7) & 7) << 4);
      bfv[ni] = *(const bf16x8*)&lds[b][1][P >> 1];
    }
    __builtin_amdgcn_s_setprio(1);
    #pragma unroll
    for (int mi = 0; mi < 4; mi++)
      #pragma unroll
      for (int ni = 0; ni < 4; ni++)
        acc[mi][ni] = __builtin_amdgcn_mfma_f32_16x16x32_bf16(af[mi], bfv[ni], acc[mi][ni], 0, 0, 0);
    __builtin_amdgcn_s_setprio(0);
  };

  stage(0); stage(1); stage(2);
  for (int t = 0; t < NT; ++t) {
    if (t < NT - 2)       asm volatile("s_waitcnt vmcnt(8)" ::: "memory");
    else if (t == NT - 2) asm volatile("s_waitcnt vmcnt(4)" ::: "memory");
    else                  asm volatile("s_waitcnt vmcnt(0)" ::: "memory");
    __builtin_amdgcn_s_barrier();
    __builtin_amdgcn_sched_barrier(0);
    if (t + 3 < NT) stage(t + 3);
    compute(t);
  }

  if (EPI == 2) {
    float* out = (float*)Cout;
    #pragma unroll
    for (int ni = 0; ni < 4; ni++) {
      int col = col0 + wn * 64 + ni * 16 + rl;
      float bv = bias[col];
      #pragma unroll
      for (int mi = 0; mi < 4; mi++) {
        int rowb = row0 + wm * 64 + mi * 16 + cg * 4;
        #pragma unroll
        for (int j = 0; j < 4; j++)
          out[(size_t)(rowb + j) * N + col] =
              acc[mi][ni][j] + bv + resid[(size_t)(rowb + j) * N + col];
      }
    }
  } else if (EPI == 3) {
    float* out = (float*)Cout + (size_t)s * M * N;
    #pragma unroll
    for (int ni = 0; ni < 4; ni++) {
      int col = col0 + wn * 64 + ni * 16 + rl;
      #pragma unroll
      for (int mi = 0; mi < 4; mi++) {
        int rowb = row0 + wm * 64 + mi * 16 + cg * 4;
        #pragma unroll
        for (int j = 0; j < 4; j++)
          out[(size_t)(rowb + j) * N + col] = acc[mi][ni][j];
      }
    }
  } else {
    ushort_t* out = (ushort_t*)Cout;
    #pragma unroll
    for (int ni = 0; ni < 4; ni++) {
      int col = col0 + wn * 64 + ni * 16 + rl;
      float bv = bias[col];
      float sc = (EPI == 0 && col < 1024) ? 0.18033688011f : 1.0f;
      #pragma unroll
      for (int mi = 0; mi < 4; mi++) {
        int rowb = row0 + wm * 64 + mi * 16 + cg * 4;
        #pragma unroll
        for (int j = 0; j < 4; j++) {
          float v = acc[mi][ni][j] + bv;
          if (EPI == 1) v = fmaxf(v, 0.0f);
          if (EPI == 0) v *= sc;
          out[(size_t)(rowb + j) * N + col] = f2bf(v);
        }
      }
    }
  }
}

// ---------------- split-K reduce: out = sum(partials) + bias + resid (fp32, N=1024) ----------------
__global__ __launch_bounds__(256) void reduce_kernel(
    const float* __restrict__ p, const float* __restrict__ bias,
    const float* __restrict__ resid, float* __restrict__ out,
    int S, size_t total4, size_t stride4) {
  const float4* p4 = (const float4*)p;
  const float4* r4 = (const float4*)resid;
  const float4* b4 = (const float4*)bias;
  float4* o4 = (float4*)out;
  for (size_t i = (size_t)blockIdx.x * 256 + threadIdx.x; i < total4;
       i += (size_t)gridDim.x * 256) {
    float4 a = r4[i];
    float4 bb = b4[i & 255];
    a.x += bb.x; a.y += bb.y; a.z += bb.z; a.w += bb.w;
    for (int s = 0; s < S; ++s) {
      float4 v = p4[(size_t)s * stride4 + i];
      a.x += v.x; a.y += v.y; a.z += v.z; a.w += v.w;
    }
    o4[i] = a;
  }
}

// ---------------- flash attention: swapped-QK^T 32x32 MFMA, in-register P ----------------
// St = mfma32(K,Q) puts P row-local (col=lane&31=q); P->A-frag redistribution is
// 16 cvt_pk + 8 v_permlane32_swap per tile (pure VALU) - no P LDS round-trip.
// Static-shift softmax (Q pre-scaled by Cs in QKV epilogue; exp2 overflow-safe).
__global__ __launch_bounds__(256) void attn_kernel(
    const ushort_t* __restrict__ qkv, const ushort_t* __restrict__ Vt,
    ushort_t* __restrict__ ctx) {
  __shared__ __align__(16) ushort_t Kl[2][64 * 64];   // [key][d] chunk-XOR, 8KB each
  __shared__ __align__(16) ushort_t Vl[2][64 * 64];   // [d][key] chunk-XOR, 8KB each
  __shared__ float Lt[4][32];
  const int tid = threadIdx.x, lane = tid & 63, wid = tid >> 6;
  // XCD swizzle over 512 wgs (16 q-tiles x 32 bh)
  int bid = blockIdx.y * 16 + blockIdx.x;
  int w = (bid & 7) * 64 + (bid >> 3);
  const int bh = w >> 4, qt = w & 15;
  const int b = bh >> 4, h = bh & 15;
  const int q0w = qt * 128 + wid * 32;
  const int k31 = lane & 31, sg = lane >> 5, x7 = k31 & 7;
  const ushort_t* Qp = qkv + (size_t)b * SS * 3072 + h * 64;
  const ushort_t* Kp = Qp + 1024;
  const ushort_t* Vg = Vt + (size_t)bh * 64 * SS;

  // Q B-frags: qf[dsl] = Q[q=q0w+k31][dsl*16 + sg*8 .. +8]
  bf16x8 qf[4];
  {
    const ushort_t* qb = Qp + (size_t)(q0w + k31) * 3072 + sg * 8;
    #pragma unroll
    for (int dsl = 0; dsl < 4; dsl++)
      qf[dsl] = *(const bf16x8*)(qb + dsl * 16);
  }
  float lsum = 0.f;
  f32x16 o0 = {}, o1 = {};

  const int NT = SS / KVBLK;

  int ksrc[2], vsrc[2];
  #pragma unroll
  for (int i = 0; i < 2; i++) {
    int idx = wid * 128 + i * 64 + lane;
    int R = idx >> 3, c = idx & 7;
    ksrc[i] = R * 3072 + ((c ^ (R & 7)) * 8);
    vsrc[i] = R * SS + ((c ^ (R & 7)) * 8);
  }
  const int ldsb = wid * 1024;

  auto stageKV = [&](int buf, int t) {
    size_t kvK = (size_t)t * KVBLK * 3072;
    int kvV = t * KVBLK;
    gload_lds16(Kp + kvK + ksrc[0], &Kl[buf][ldsb]);
    gload_lds16(Kp + kvK + ksrc[1], &Kl[buf][ldsb + 512]);
    gload_lds16(Vg + kvV + vsrc[0], &Vl[buf][ldsb]);
    gload_lds16(Vg + kvV + vsrc[1], &Vl[buf][ldsb + 512]);
  };

  // exp + pack + permlane-swap one 32-key half into two PV A-frags
  auto softmax_half = [&](const f32x16& s, bf16x8& paE, bf16x8& paO) {
    float pv[16];
    #pragma unroll
    for (int r = 0; r < 16; r++) pv[r] = __builtin_amdgcn_exp2f(s[r]);
    #pragma unroll
    for (int r = 0; r < 16; r++) lsum += pv[r];
    unsigned W[4][2];
    #pragma unroll
    for (int qd = 0; qd < 4; qd++) {
      asm("v_cvt_pk_bf16_f32 %0, %1, %2" : "=v"(W[qd][0]) : "v"(pv[4 * qd]), "v"(pv[4 * qd + 1]));
      asm("v_cvt_pk_bf16_f32 %0, %1, %2" : "=v"(W[qd][1]) : "v"(pv[4 * qd + 2]), "v"(pv[4 * qd + 3]));
    }
    unsigned a0 = W[1][0], b0 = W[0][0], a1 = W[1][1], b1 = W[0][1];
    asm("v_permlane32_swap_b32 %0, %1" : "+v"(a0), "+v"(b0));
    asm("v_permlane32_swap_b32 %0, %1" : "+v"(a1), "+v"(b1));
    paE = pack4w(b0, b1, a0, a1);
    unsigned a2 = W[3][0], b2 = W[2][0], a3 = W[3][1], b3 = W[2][1];
    asm("v_permlane32_swap_b32 %0, %1" : "+v"(a2), "+v"(b2));
    asm("v_permlane32_swap_b32 %0, %1" : "+v"(a3), "+v"(b3));
    paO = pack4w(b2, b3, a2, a3);
  };

  auto body = [&](int t, int cb) {
    __syncthreads();
    if (t + 1 < NT) stageKV(cb ^ 1, t + 1);

    // swapped QK^T: s[kh][reg] = S[key = kh*32 + (reg&3)+8*(reg>>2)+4*sg][q = k31]
    f32x16 s0 = {}, s1 = {};
    #pragma unroll
    for (int dsl = 0; dsl < 4; dsl++) {
      int ch = ((dsl * 2 + sg) ^ x7) * 8;
      bf16x8 kf0 = *(const bf16x8*)(&Kl[cb][k31 * 64 + ch]);
      bf16x8 kf1 = *(const bf16x8*)(&Kl[cb][(32 + k31) * 64 + ch]);
      s0 = __builtin_amdgcn_mfma_f32_32x32x16_bf16(kf0, qf[dsl], s0, 0, 0, 0);
      s1 = __builtin_amdgcn_mfma_f32_32x32x16_bf16(kf1, qf[dsl], s1, 0, 0, 0);
    }
    bf16x8 pa[4];
    softmax_half(s0, pa[0], pa[1]);
    softmax_half(s1, pa[2], pa[3]);
    // PV: o[dh] += P[32q][16k-block ks] * V[ks][d-half dh]
    #pragma unroll
    for (int ks = 0; ks < 4; ks++) {
      int ch = ((2 * ks + sg) ^ x7) * 8;
      bf16x8 vf0 = *(const bf16x8*)(&Vl[cb][k31 * 64 + ch]);
      bf16x8 vf1 = *(const bf16x8*)(&Vl[cb][(32 + k31) * 64 + ch]);
      o0 = __builtin_amdgcn_mfma_f32_32x32x16_bf16(pa[ks], vf0, o0, 0, 0, 0);
      o1 = __builtin_amdgcn_mfma_f32_32x32x16_bf16(pa[ks], vf1, o1, 0, 0, 0);
    }
  };

  stageKV(0, 0);
  for (int t = 0; t < NT; t += 2) {
    body(t, 0);
    body(t + 1, 1);
  }

  // row sums: lane has partial for q=k31; combine with partner, table in LDS
  float ltot = lsum + __shfl_xor(lsum, 32);
  if (lane < 32) Lt[wid][lane] = ltot;
  asm volatile("s_waitcnt lgkmcnt(0)" ::: "memory");
  __builtin_amdgcn_sched_barrier(0);

  const int colb = h * 64 + k31;
  #pragma unroll
  for (int r = 0; r < 16; r++) {
    int qp = (r & 3) + 8 * (r >> 2) + 4 * sg;
    float rlq = 1.0f / Lt[wid][qp];
    size_t row = (size_t)(b * SS + q0w + qp);
    ctx[row * D_MODEL + colb] = f2bf(o0[r] * rlq);
    ctx[row * D_MODEL + colb + 32] = f2bf(o1[r] * rlq);
  }
}

extern "C" void kernel_launch(void* const* d_in, const int* in_sizes, int n_in,
                              void* d_out, int out_size, void* d_ws, size_t ws_size,
                              hipStream_t stream) {
  const float* x    = (const float*)d_in[0];
  const float* ln1w = (const float*)d_in[1];
  const float* ln1b = (const float*)d_in[2];
  const float* Wq   = (const float*)d_in[3];
  const float* bq   = (const float*)d_in[4];
  const float* Wk   = (const float*)d_in[5];
  const float* bk   = (const float*)d_in[6];
  const float* Wv   = (const float*)d_in[7];
  const float* bv   = (const float*)d_in[8];
  const float* Wo   = (const float*)d_in[9];
  const float* bo   = (const float*)d_in[10];
  const float* ln2w = (const float*)d_in[11];
  const float* ln2b = (const float*)d_in[12];
  const float* W1   = (const float*)d_in[13];
  const float* b1   = (const float*)d_in[14];
  const float* W2   = (const float*)d_in[15];
  const float* b2   = (const float*)d_in[16];

  char* ws = (char*)d_ws;
  size_t off = 0;
  auto alloc = [&](size_t bytes) {
    void* p = ws + off;
    off += (bytes + 255) & ~(size_t)255;
    return p;
  };
  ushort_t* Wt_qkv = (ushort_t*)alloc((size_t)3072 * 1024 * 2);
  ushort_t* Wt_o   = (ushort_t*)alloc((size_t)1024 * 1024 * 2);
  ushort_t* Wt_1   = (ushort_t*)alloc((size_t)4096 * 1024 * 2);
  ushort_t* Wt_2   = (ushort_t*)alloc((size_t)1024 * 4096 * 2);
  float*    bqkv   = (float*)alloc((size_t)3072 * 4);
  ushort_t* qkvb   = (ushort_t*)alloc((size_t)MROWS * 3072 * 2);  // 24 MB
  ushort_t* ctxb   = (ushort_t*)alloc((size_t)MROWS * 1024 * 2);  // 8 MB
  ushort_t* hbuf   = (ushort_t*)alloc((size_t)MROWS * 1024 * 2);
  float*    x2     = (float*)alloc((size_t)MROWS * 1024 * 4);
  ushort_t* Vtb    = (ushort_t*)alloc((size_t)BB * NH * 64 * SS * 2);  // 8 MB
  ushort_t* ff1    = qkvb;  // reuse qkv(24MB)+ctx(8MB) = 32MB for [4096][4096] bf16
  float*    outp   = (float*)d_out;

  // split-K=2 partials for FFN2 (32 MB); fallback to fused if no room
  const size_t partial1 = (size_t)MROWS * 1024 * 4;  // 16 MB per split
  int S = (ws_size - off >= 2 * partial1 + 256) ? 2 : 1;
  float* pbuf = (S == 2) ? (float*)alloc(2 * partial1) : nullptr;

  dim3 tb(32, 8);
  transpose_cast_kernel<<<dim3(32, 32), tb, 0, stream>>>(Wq, Wt_qkv, 1024, 1024);
  transpose_cast_kernel<<<dim3(32, 32), tb, 0, stream>>>(Wk, Wt_qkv + 1024 * 1024, 1024, 1024);
  transpose_cast_kernel<<<dim3(32, 32), tb, 0, stream>>>(Wv, Wt_qkv + 2 * 1024 * 1024, 1024, 1024);
  transpose_cast_kernel<<<dim3(32, 32), tb, 0, stream>>>(Wo, Wt_o, 1024, 1024);
  transpose_cast_kernel<<<dim3(128, 32), tb, 0, stream>>>(W1, Wt_1, 1024, 4096);
  transpose_cast_kernel<<<dim3(32, 128), tb, 0, stream>>>(W2, Wt_2, 4096, 1024);
  hipMemcpyAsync(bqkv,        bq, 1024 * 4, hipMemcpyDeviceToDevice, stream);
  hipMemcpyAsync(bqkv + 1024, bk, 1024 * 4, hipMemcpyDeviceToDevice, stream);
  hipMemcpyAsync(bqkv + 2048, bv, 1024 * 4, hipMemcpyDeviceToDevice, stream);

  // LN1 -> h
  ln_bf16_kernel<<<MROWS, 256, 0, stream>>>(x, ln1w, ln1b, hbuf);
  // fused QKV GEMM: [4096,1024]x[1024,3072] -> bf16 (Q cols pre-scaled by Cs)
  gemm128_kernel<0><<<dim3(24 * 32), 256, 0, stream>>>(
      hbuf, Wt_qkv, bqkv, nullptr, qkvb, MROWS, 3072, 1024, 24, 1024, 24 * 32);
  // V transpose -> Vt[bh][64][2048]
  vtrans_kernel<<<dim3(SS / 64, BB * NH), 256, 0, stream>>>(qkvb, Vtb);
  // attention: 128 q/block, 512 blocks
  attn_kernel<<<dim3(SS / 128, BB * NH), 256, 0, stream>>>(qkvb, Vtb, ctxb);
  // O-proj + bias + residual(x) -> x2 (fp32), fused
  gemm128_kernel<2><<<dim3(8 * 32), 256, 0, stream>>>(
      ctxb, Wt_o, bo, x, x2, MROWS, 1024, 1024, 8, 1024, 8 * 32);
  // LN2 -> h
  ln_bf16_kernel<<<MROWS, 256, 0, stream>>>(x2, ln2w, ln2b, hbuf);
  // FFN1 + relu -> ff1 (bf16)
  gemm128_kernel<1><<<dim3(32 * 32), 256, 0, stream>>>(
      hbuf, Wt_1, b1, nullptr, ff1, MROWS, D_FF, 1024, 32, 1024, 32 * 32);
  // FFN2: split-K=2 -> fp32 partials; reduce adds bias b2 + resid x2 -> out
  if (S == 2) {
    gemm128_kernel<3><<<dim3(8 * 32 * 2), 256, 0, stream>>>(
        ff1, Wt_2, nullptr, nullptr, pbuf, MROWS, 1024, 4096, 8, 2048, 8 * 32);
    reduce_kernel<<<2048, 256, 0, stream>>>(pbuf, b2, x2, outp, 2,
        (size_t)MROWS * 1024 / 4, (size_t)MROWS * 1024 / 4);
  } else {
    gemm128_kernel<2><<<dim3(8 * 32), 256, 0, stream>>>(
        ff1, Wt_2, b2, x2, outp, MROWS, 1024, 4096, 8, 4096, 8 * 32);
  }
}